// Round 5
// baseline (531.528 us; speedup 1.0000x reference)
//
#include <hip/hip_runtime.h>
#include <cmath>

#define F_IN 500
#define HD 64
#define NL 8
#define NRANK 3
#define NOUT 40
#define NGRP 300   // 297 real (m,l0) groups of 8 + 3 zero pads -> K = 2400
#define NCHUNK 75  // 2400 / 32

typedef __attribute__((ext_vector_type(8))) short short8v;
typedef __attribute__((ext_vector_type(4))) float float4v;

__device__ __forceinline__ float bf2f(ushort u) {
  union { unsigned int i; float f; } v;
  v.i = ((unsigned int)u) << 16;
  return v.f;
}
__device__ __forceinline__ ushort f2bf(float f) {
  union { float f; unsigned int i; } v;
  v.f = f;
  unsigned int b = v.i;
  return (ushort)((b + 0x7FFFu + ((b >> 16) & 1u)) >> 16);
}

// ---------------- zero init ----------------
__global__ __launch_bounds__(256) void k_zero(int* counts, float* linbuf, float* cbuf,
                                              ushort4* bfrag4, int N) {
  int i = blockIdx.x * 256 + threadIdx.x;
  if (i < N) counts[i] = 0;
  if (i < NOUT * HD) linbuf[i] = 0.f;
  if (i < NOUT) cbuf[i] = 0.f;
  if (i < NCHUNK * 3 * 64 * 2) bfrag4[i] = make_ushort4(0, 0, 0, 0);
}

__global__ __launch_bounds__(256) void k_count(const int* __restrict__ row, int* counts, int E) {
  int e = blockIdx.x * 256 + threadIdx.x;
  if (e < E) atomicAdd(&counts[row[e]], 1);
}

// ---------------- parallel scan (3 kernels) ----------------
__global__ __launch_bounds__(1024) void k_scan1(const int* __restrict__ counts, int* __restrict__ rowptr,
                                                int* __restrict__ bsum, int N) {
  __shared__ int sh[1024];
  int t = threadIdx.x, i = blockIdx.x * 1024 + t;
  int c = (i < N) ? counts[i] : 0;
  sh[t] = c;
  __syncthreads();
  for (int d = 1; d < 1024; d <<= 1) {
    int v = (t >= d) ? sh[t - d] : 0;
    __syncthreads();
    sh[t] += v;
    __syncthreads();
  }
  if (i < N) rowptr[i] = sh[t] - c;  // block-local exclusive
  if (t == 1023) bsum[blockIdx.x] = sh[1023];
}

__global__ __launch_bounds__(64) void k_scan2(const int* __restrict__ bsum, int* __restrict__ boff, int G) {
  int t = threadIdx.x;
  int base = 0;
  for (int s = 0; s < G; s += 64) {
    int i = s + t;
    int v = (i < G) ? bsum[i] : 0;
    int orig = v;
    for (int d = 1; d < 64; d <<= 1) {
      int u = __shfl_up(v, d, 64);
      if (t >= d) v += u;
    }
    if (i < G) boff[i] = base + v - orig;
    base += __shfl(v, 63, 64);
  }
}

__global__ __launch_bounds__(1024) void k_scan3(int* __restrict__ rowptr, int* __restrict__ cursor,
                                                const int* __restrict__ boff, int N, int E) {
  int i = blockIdx.x * 1024 + threadIdx.x;
  if (i < N) {
    int v = rowptr[i] + boff[blockIdx.x];
    rowptr[i] = v;
    cursor[i] = v;
  }
  if (i == 0) rowptr[N] = E;
}

__global__ __launch_bounds__(256) void k_fill(const int* __restrict__ row, const int* __restrict__ col,
                                              const float* __restrict__ w, int* cursor,
                                              int2* __restrict__ colw, int E) {
  int e = blockIdx.x * 256 + threadIdx.x;
  if (e < E) {
    int r = row[e];
    int p = atomicAdd(&cursor[r], 1);
    colw[p] = make_int2(col[e], __float_as_int(w[e]));
  }
}

// ---------------- W_in -> bf16 [64 cols][512 k], zero-padded ----------------
__global__ __launch_bounds__(256) void k_wcvt(const float* __restrict__ W, ushort* __restrict__ Wbf) {
  int i = blockIdx.x * 256 + threadIdx.x;
  if (i >= 64 * 512) return;
  int d = i >> 9, k = i & 511;
  Wbf[i] = (k < F_IN) ? f2bf(W[(size_t)k * HD + d]) : (ushort)0;
}

// ---------------- input GEMM via MFMA, split-K over 4 waves + LDS reduce ----------------
__global__ __launch_bounds__(256) void k_gemm_in(const float* __restrict__ x,
                                                 const ushort* __restrict__ Wbf,
                                                 const float* __restrict__ b,
                                                 ushort* __restrict__ h0bf, int N) {
  __shared__ float red[4][64][17];
  int tid = threadIdx.x;
  int w = tid >> 6, lane = tid & 63;
  int c15 = lane & 15, g4 = lane >> 4;
  int rowA = blockIdx.x * 16 + c15;
  if (rowA >= N) rowA = N - 1;  // clamp; results discarded at store
  const float* xr = x + (size_t)rowA * F_IN;
  int koff = g4 * 8;
  float4v acc[4];
#pragma unroll
  for (int ct = 0; ct < 4; ++ct) acc[ct] = (float4v){0.f, 0.f, 0.f, 0.f};
#pragma unroll
  for (int kk = 0; kk < 4; ++kk) {
    int kc = w * 4 + kk;  // wave-uniform
    int kbase = kc * 32 + koff;
    short8v a;
    if (kc < 15) {
      float4 f0 = *(const float4*)(xr + kbase);
      float4 f1 = *(const float4*)(xr + kbase + 4);
      a[0] = (short)f2bf(f0.x); a[1] = (short)f2bf(f0.y);
      a[2] = (short)f2bf(f0.z); a[3] = (short)f2bf(f0.w);
      a[4] = (short)f2bf(f1.x); a[5] = (short)f2bf(f1.y);
      a[6] = (short)f2bf(f1.z); a[7] = (short)f2bf(f1.w);
    } else {
#pragma unroll
      for (int e = 0; e < 8; ++e) {
        int k = kbase + e;
        a[e] = (short)(k < F_IN ? f2bf(xr[k]) : (ushort)0);
      }
    }
#pragma unroll
    for (int ct = 0; ct < 4; ++ct) {
      const short8v bb = *(const short8v*)&Wbf[((ct * 16 + c15) << 9) + kbase];
      acc[ct] = __builtin_amdgcn_mfma_f32_16x16x32_bf16(a, bb, acc[ct], 0, 0, 0);
    }
  }
#pragma unroll
  for (int ct = 0; ct < 4; ++ct)
#pragma unroll
    for (int r = 0; r < 4; ++r) red[w][lane][ct * 4 + r] = acc[ct][r];
  __syncthreads();
  int l = tid >> 2, ct = tid & 3;
  int g4r = l >> 4, c15r = l & 15;
  int d = ct * 16 + c15r;
  float bias = b[d];
#pragma unroll
  for (int r = 0; r < 4; ++r) {
    int i = ct * 4 + r;
    float s = (red[0][l][i] + red[1][l][i]) + (red[2][l][i] + red[3][l][i]);
    int m = blockIdx.x * 16 + g4r * 4 + r;
    if (m < N) h0bf[(size_t)m * HD + d] = f2bf(fmaxf(s + bias, 0.f));
  }
}

// ---------------- GCN2 layer: branchless 16-deep gather pipeline, 2 rows/wave ----------------
__global__ __launch_bounds__(256) void k_layer(const ushort* __restrict__ hin,
                                               const ushort* __restrict__ h0bf,
                                               const int* __restrict__ rowptr, const int2* __restrict__ colw,
                                               const float* __restrict__ convW, float beta,
                                               ushort* __restrict__ hout, int N) {
  __shared__ float Ml[64][64];          // (1-b)I + b*W
  __shared__ float sup[4][2][64];
  __shared__ int2 ec[4][2][64];
  int tid = threadIdx.x, wv = tid >> 6, t = tid & 63;
  for (int idx = tid; idx < 4096; idx += 256) {
    int i = idx >> 6, j = idx & 63;
    Ml[i][j] = beta * convW[idx] + ((i == j) ? (1.f - beta) : 0.f);
  }
  __syncthreads();
  int nA = blockIdx.x * 8 + wv * 2;
  int nB = nA + 1;
  int e0A = 0, e1A = 0, e0B = 0, e1B = 0;
  if (nA < N) { e0A = rowptr[nA]; e1A = rowptr[nA + 1]; }
  if (nB < N) { e0B = rowptr[nB]; e1B = rowptr[nB + 1]; }
  int degA = e1A - e0A, degB = e1B - e0B;
  int degM = degA > degB ? degA : degB;
  float aA[4] = {0.f, 0.f, 0.f, 0.f}, aB[4] = {0.f, 0.f, 0.f, 0.f};
  for (int base = 0; base < degM; base += 64) {
    int rA = degA - base, rB = degB - base;
    // stage 64 edges per row, zero-padded (col=0, w=0 -> harmless)
    ec[wv][0][t] = (t < rA) ? colw[e0A + base + t] : make_int2(0, 0);
    ec[wv][1][t] = (t < rB) ? colw[e0B + base + t] : make_int2(0, 0);
    int cM = rA > rB ? rA : rB;
    cM = cM > 64 ? 64 : cM;
    cM = (cM + 7) & ~7;  // round up; padded entries are zero-weight
    for (int j = 0; j < cM; j += 8) {
      int2 eAr[8], eBr[8];
#pragma unroll
      for (int k = 0; k < 8; ++k) eAr[k] = ec[wv][0][j + k];
#pragma unroll
      for (int k = 0; k < 8; ++k) eBr[k] = ec[wv][1][j + k];
      float gA[8], gB[8];
#pragma unroll
      for (int k = 0; k < 8; ++k) gA[k] = bf2f(hin[(size_t)eAr[k].x * HD + t]);
#pragma unroll
      for (int k = 0; k < 8; ++k) gB[k] = bf2f(hin[(size_t)eBr[k].x * HD + t]);
#pragma unroll
      for (int k = 0; k < 8; ++k) aA[k & 3] = fmaf(__int_as_float(eAr[k].y), gA[k], aA[k & 3]);
#pragma unroll
      for (int k = 0; k < 8; ++k) aB[k & 3] = fmaf(__int_as_float(eBr[k].y), gB[k], aB[k & 3]);
    }
  }
  if (nA < N)
    sup[wv][0][t] = 0.9f * ((aA[0] + aA[1]) + (aA[2] + aA[3])) + 0.1f * bf2f(h0bf[(size_t)nA * HD + t]);
  if (nB < N)
    sup[wv][1][t] = 0.9f * ((aB[0] + aB[1]) + (aB[2] + aB[3])) + 0.1f * bf2f(h0bf[(size_t)nB * HD + t]);
  // matvec: same wave reads its own sup -> no block barrier needed
  if (nA < N) {
    float mv = 0.f;
#pragma unroll
    for (int h = 0; h < 64; ++h) mv = fmaf(sup[wv][0][h], Ml[h][t], mv);
    hout[(size_t)nA * HD + t] = f2bf(fmaxf(mv, 0.f));
  }
  if (nB < N) {
    float mv = 0.f;
#pragma unroll
    for (int h = 0; h < 64; ++h) mv = fmaf(sup[wv][1][h], Ml[h][t], mv);
    hout[(size_t)nB * HD + t] = f2bf(fmaxf(mv, 0.f));
  }
}

// ---------------- group table: g -> (m, l0) ----------------
__global__ __launch_bounds__(512) void k_gtab(int2* __restrict__ gtab) {
  int g = threadIdx.x;
  if (g >= NGRP) return;
  int m = 64, l0 = 65;
  if (g < 297) {
    int cum = 0;
    for (int mm = 0; mm < 65; ++mm) {
      int ng = (65 - mm + 7) >> 3;
      if (g < cum + ng) { m = mm; l0 = mm + (g - cum) * 8; break; }
      cum += ng;
    }
  }
  gtab[g] = make_int2(m, l0);
}

// ---------------- T[r,o] = Wo_o @ V_r^T  (+ linear/const bias terms) ----------------
__global__ __launch_bounds__(256) void k_T(const float* __restrict__ W_out, const float* __restrict__ V_W,
                                           const float* __restrict__ V_b, const float* __restrict__ U_W,
                                           const float* __restrict__ U_b,
                                           float* __restrict__ Tbuf, float* linbuf, float* cbuf) {
  int o = blockIdx.x % NOUT;
  int r = blockIdx.x / NOUT;
  __shared__ float Wo[64][65];
  __shared__ float Vs[64][65];
  __shared__ float t1[64], t2[64];
  int tid = threadIdx.x;
  int tx = tid & 15, ty = tid >> 4;
  for (int idx = tid; idx < 4096; idx += 256) {
    int m = idx >> 6, l = idx & 63;
    Wo[m][l] = W_out[(size_t)idx * NOUT + o];
    Vs[m][l] = V_W[(size_t)(r * 64 + m) * 64 + l];
  }
  __syncthreads();
  float acc[4][4] = {};
  for (int l = 0; l < 64; ++l) {
    float av[4], bv[4];
#pragma unroll
    for (int i = 0; i < 4; ++i) av[i] = Wo[ty * 4 + i][l];
#pragma unroll
    for (int j = 0; j < 4; ++j) bv[j] = Vs[tx * 4 + j][l];
#pragma unroll
    for (int i = 0; i < 4; ++i)
#pragma unroll
      for (int j = 0; j < 4; ++j) acc[i][j] = fmaf(av[i], bv[j], acc[i][j]);
  }
#pragma unroll
  for (int i = 0; i < 4; ++i)
#pragma unroll
    for (int j = 0; j < 4; ++j)
      Tbuf[(((size_t)r * NOUT + o) * 64 + ty * 4 + i) * 64 + tx * 4 + j] = acc[i][j];
  if (tid < 64) {
    float s1 = 0.f, s2 = 0.f;
    for (int l = 0; l < 64; ++l) s1 = fmaf(Wo[tid][l], V_b[r * 64 + l], s1);
    for (int m = 0; m < 64; ++m) s2 = fmaf(Wo[m][tid], U_b[r * 64 + m], s2);
    t1[tid] = s1;
    t2[tid] = s2;
  }
  __syncthreads();
  if (tid < 64) {
    float s = 0.f, s2 = 0.f;
    for (int m = 0; m < 64; ++m) s = fmaf(U_W[(size_t)(r * 64 + tid) * 64 + m], t1[m], s);
    for (int l = 0; l < 64; ++l) s2 = fmaf(Vs[tid][l], t2[l], s2);
    atomicAdd(&linbuf[o * 64 + tid], s + s2);
  }
  if (tid == 0) {
    float s = 0.f;
    for (int m = 0; m < 64; ++m) s = fmaf(U_b[r * 64 + m], t1[m], s);
    atomicAdd(&cbuf[o], s);
  }
}

// ---------------- Q_o = sum_r U_r @ T[r,o]; pack bf16 B-fragments ----------------
__global__ __launch_bounds__(256) void k_Q(const float* __restrict__ U_W, const float* __restrict__ Tbuf,
                                           const float* __restrict__ linbuf, const float* __restrict__ cbuf,
                                           const float* __restrict__ b_out,
                                           const int2* __restrict__ gtab, ushort* __restrict__ Bfrag) {
  int o = blockIdx.x;
  __shared__ float Us[64][65];
  __shared__ float Tb[64][65];
  __shared__ float Q[64][65];
  int tid = threadIdx.x, tx = tid & 15, ty = tid >> 4;
  float acc[4][4] = {};
  for (int r = 0; r < NRANK; ++r) {
    for (int idx = tid; idx < 4096; idx += 256) {
      int a = idx >> 6, mm = idx & 63;
      Us[a][mm] = U_W[(size_t)(r * 64 + a) * 64 + mm];
      Tb[a][mm] = Tbuf[(((size_t)r * NOUT + o) * 64 + a) * 64 + mm];
    }
    __syncthreads();
    for (int mm = 0; mm < 64; ++mm) {
      float av[4], bv[4];
#pragma unroll
      for (int i = 0; i < 4; ++i) av[i] = Us[ty * 4 + i][mm];
#pragma unroll
      for (int j = 0; j < 4; ++j) bv[j] = Tb[mm][tx * 4 + j];
#pragma unroll
      for (int i = 0; i < 4; ++i)
#pragma unroll
        for (int j = 0; j < 4; ++j) acc[i][j] = fmaf(av[i], bv[j], acc[i][j]);
    }
    __syncthreads();
  }
#pragma unroll
  for (int i = 0; i < 4; ++i)
#pragma unroll
    for (int j = 0; j < 4; ++j) Q[ty * 4 + i][tx * 4 + j] = acc[i][j];
  __syncthreads();
  int ot = o >> 4, o15 = o & 15;
  for (int idx = tid; idx < NGRP * 8; idx += 256) {
    int g = idx >> 3, e = idx & 7;
    int2 ml = gtab[g];
    int m = ml.x, l = ml.y + e;
    float v;
    if (l < 64) v = (m == l) ? Q[m][m] : Q[m][l] + Q[l][m];
    else if (l == 64) v = (m == 64) ? (cbuf[o] + b_out[o]) : linbuf[o * 64 + m];
    else v = 0.f;
    int c = g >> 2, g4 = g & 3;
    Bfrag[((((size_t)c * 3 + ot) * 64) + g4 * 16 + o15) * 8 + e] = f2bf(v);
  }
}

// ---------------- logits via MFMA + fused expmap0/proj/log_softmax ----------------
__global__ __launch_bounds__(256) void k_logits(const ushort* __restrict__ hbf,
                                                const ushort* __restrict__ Bfrag,
                                                const int2* __restrict__ gtab,
                                                float* __restrict__ out, int N) {
  __shared__ float eh[128][77];
  __shared__ int2 gs[NGRP];
  int tid = threadIdx.x;
  int n0 = blockIdx.x * 128;
  for (int idx = tid; idx < 128 * 16; idx += 256) {
    int n = idx >> 4, f4 = (idx & 15) << 2;
    int gn = n0 + n;
    float v0 = 0.f, v1 = 0.f, v2 = 0.f, v3 = 0.f;
    if (gn < N) {
      ushort4 u = *(const ushort4*)&hbf[(size_t)gn * HD + f4];
      v0 = bf2f(u.x); v1 = bf2f(u.y); v2 = bf2f(u.z); v3 = bf2f(u.w);
    }
    eh[n][f4] = v0; eh[n][f4 + 1] = v1; eh[n][f4 + 2] = v2; eh[n][f4 + 3] = v3;
  }
  for (int idx = tid; idx < 128 * 13; idx += 256) {
    int n = idx / 13, j = idx - n * 13;
    eh[n][64 + j] = (j == 0) ? 1.f : 0.f;
  }
  for (int idx = tid; idx < NGRP; idx += 256) gs[idx] = gtab[idx];
  __syncthreads();

  int w = tid >> 6, lane = tid & 63;
  int g4 = lane >> 4, c15 = lane & 15;
  float4v acc[2][3];
#pragma unroll
  for (int t = 0; t < 2; ++t)
#pragma unroll
    for (int ot = 0; ot < 3; ++ot) acc[t][ot] = (float4v){0.f, 0.f, 0.f, 0.f};
  const float* ehr0 = &eh[(w * 2 + 0) * 16 + c15][0];
  const float* ehr1 = &eh[(w * 2 + 1) * 16 + c15][0];

  for (int c = 0; c < NCHUNK; ++c) {
    const short8v b0 = *(const short8v*)&Bfrag[(((size_t)c * 3 + 0) * 64 + lane) * 8];
    const short8v b1 = *(const short8v*)&Bfrag[(((size_t)c * 3 + 1) * 64 + lane) * 8];
    const short8v b2 = *(const short8v*)&Bfrag[(((size_t)c * 3 + 2) * 64 + lane) * 8];
    int2 ml = gs[c * 4 + g4];
    int m = ml.x, l0 = ml.y;
    float hm0 = ehr0[m], hm1 = ehr1[m];
    short8v a0, a1;
#pragma unroll
    for (int e = 0; e < 8; ++e) {
      a0[e] = (short)f2bf(hm0 * ehr0[l0 + e]);
      a1[e] = (short)f2bf(hm1 * ehr1[l0 + e]);
    }
    acc[0][0] = __builtin_amdgcn_mfma_f32_16x16x32_bf16(a0, b0, acc[0][0], 0, 0, 0);
    acc[1][0] = __builtin_amdgcn_mfma_f32_16x16x32_bf16(a1, b0, acc[1][0], 0, 0, 0);
    acc[0][1] = __builtin_amdgcn_mfma_f32_16x16x32_bf16(a0, b1, acc[0][1], 0, 0, 0);
    acc[1][1] = __builtin_amdgcn_mfma_f32_16x16x32_bf16(a1, b1, acc[1][1], 0, 0, 0);
    acc[0][2] = __builtin_amdgcn_mfma_f32_16x16x32_bf16(a0, b2, acc[0][2], 0, 0, 0);
    acc[1][2] = __builtin_amdgcn_mfma_f32_16x16x32_bf16(a1, b2, acc[1][2], 0, 0, 0);
  }

  __syncthreads();  // all eh reads done; reuse as logits tile [128][41]
  float* ls = &eh[0][0];
#pragma unroll
  for (int t = 0; t < 2; ++t) {
    int rbase = (w * 2 + t) * 16 + g4 * 4;
#pragma unroll
    for (int ot = 0; ot < 3; ++ot) {
      int o = ot * 16 + c15;
      if (o < NOUT) {
#pragma unroll
        for (int r = 0; r < 4; ++r) ls[(rbase + r) * 41 + o] = acc[t][ot][r];
      }
    }
  }
  __syncthreads();
  if (tid < 128) {
    int n = n0 + tid;
    if (n < N) {
      float v[40];
      float s = 0.f;
#pragma unroll
      for (int i = 0; i < 40; ++i) { v[i] = ls[tid * 41 + i]; s = fmaf(v[i], v[i], s); }
      float un = fmaxf(sqrtf(s), 1e-15f);
      float sc = tanhf(un) / un;
      float s2 = 0.f;
#pragma unroll
      for (int i = 0; i < 40; ++i) { v[i] *= sc; s2 = fmaf(v[i], v[i], s2); }
      float ny = fmaxf(sqrtf(s2), 1e-15f);
      float maxn = 1.0f - 4e-3f;
      if (ny > maxn) {
        float f = maxn / ny;
#pragma unroll
        for (int i = 0; i < 40; ++i) v[i] *= f;
      }
      float vmax = v[0];
#pragma unroll
      for (int i = 1; i < 40; ++i) vmax = fmaxf(vmax, v[i]);
      float se = 0.f;
#pragma unroll
      for (int i = 0; i < 40; ++i) se += expf(v[i] - vmax);
      float lse = logf(se) + vmax;
      float4* q = (float4*)(out + (size_t)n * NOUT);
#pragma unroll
      for (int i = 0; i < 10; ++i) {
        float4 t;
        t.x = v[4 * i] - lse;
        t.y = v[4 * i + 1] - lse;
        t.z = v[4 * i + 2] - lse;
        t.w = v[4 * i + 3] - lse;
        q[i] = t;
      }
    }
  }
}

extern "C" void kernel_launch(void* const* d_in, const int* in_sizes, int n_in,
                              void* d_out, int out_size, void* d_ws, size_t ws_size,
                              hipStream_t stream) {
  const float* x = (const float*)d_in[0];
  const int* erow = (const int*)d_in[1];
  const int* ecol = (const int*)d_in[2];
  const float* ew = (const float*)d_in[3];
  const float* W_in = (const float*)d_in[4];
  const float* b_in = (const float*)d_in[5];
  const float* conv_W = (const float*)d_in[6];
  const float* U_W = (const float*)d_in[7];
  const float* U_b = (const float*)d_in[8];
  const float* V_W = (const float*)d_in[9];
  const float* V_b = (const float*)d_in[10];
  const float* W_out = (const float*)d_in[11];
  const float* b_out = (const float*)d_in[12];
  int N = in_sizes[0] / F_IN;
  int E = in_sizes[1];
  float* out = (float*)d_out;

  char* base = (char*)d_ws;
  size_t off = 0;
  auto alloc = [&](size_t bytes) -> void* {
    void* p = base + off;
    off += (bytes + 255) & ~(size_t)255;
    return p;
  };
  ushort* h0bf = (ushort*)alloc((size_t)N * HD * 2);
  ushort* hbfA = (ushort*)alloc((size_t)N * HD * 2);
  ushort* hbfB = (ushort*)alloc((size_t)N * HD * 2);
  int* rowptr = (int*)alloc((size_t)(N + 1) * 4);
  int* cursor = (int*)alloc((size_t)N * 4);
  int* counts = (int*)alloc((size_t)N * 4);
  int2* colw = (int2*)alloc((size_t)E * 8);
  float* Tbuf = (float*)alloc((size_t)NRANK * NOUT * 64 * 64 * 4);
  ushort* Bfrag = (ushort*)alloc((size_t)NCHUNK * 3 * 64 * 8 * 2);
  ushort* Wbf = (ushort*)alloc((size_t)64 * 512 * 2);
  float* linbuf = (float*)alloc(NOUT * 64 * 4);
  float* cbuf = (float*)alloc(NOUT * 4);
  int2* gtab = (int2*)alloc(NGRP * 8);
  int* bsum = (int*)alloc(64 * 4);
  int* boff = (int*)alloc(64 * 4);

  int G = (N + 1023) / 1024;

  k_zero<<<(N + 255) / 256, 256, 0, stream>>>(counts, linbuf, cbuf, (ushort4*)Bfrag, N);
  k_count<<<(E + 255) / 256, 256, 0, stream>>>(erow, counts, E);
  k_scan1<<<G, 1024, 0, stream>>>(counts, rowptr, bsum, N);
  k_scan2<<<1, 64, 0, stream>>>(bsum, boff, G);
  k_scan3<<<G, 1024, 0, stream>>>(rowptr, cursor, boff, N, E);
  k_fill<<<(E + 255) / 256, 256, 0, stream>>>(erow, ecol, ew, cursor, colw, E);
  k_wcvt<<<128, 256, 0, stream>>>(W_in, Wbf);
  k_gemm_in<<<(N + 15) / 16, 256, 0, stream>>>(x, Wbf, b_in, h0bf, N);
  k_gtab<<<1, 512, 0, stream>>>(gtab);
  k_T<<<NRANK * NOUT, 256, 0, stream>>>(W_out, V_W, V_b, U_W, U_b, Tbuf, linbuf, cbuf);
  k_Q<<<NOUT, 256, 0, stream>>>(U_W, Tbuf, linbuf, cbuf, b_out, gtab, Bfrag);

  const ushort* hin = h0bf;
  ushort* hout = hbfA;
  for (int l = 0; l < NL; ++l) {
    float beta = (float)std::log(0.5 / (double)(l + 1) + 1.0);
    k_layer<<<(N + 7) / 8, 256, 0, stream>>>(hin, h0bf, rowptr, colw,
                                             conv_W + (size_t)l * HD * HD,
                                             beta, hout, N);
    hin = hout;
    hout = (hout == hbfA) ? hbfB : hbfA;
  }
  k_logits<<<(N + 127) / 128, 256, 0, stream>>>(hin, Bfrag, gtab, out, N);
}

// Round 6
// 529.047 us; speedup vs baseline: 1.0047x; 1.0047x over previous
//
#include <hip/hip_runtime.h>
#include <cmath>

#define F_IN 500
#define HD 64
#define NL 8
#define NRANK 3
#define NOUT 40
#define NGRP 300   // 297 real (m,l0) groups of 8 + 3 zero pads -> K = 2400
#define NCHUNK 75  // 2400 / 32

typedef __attribute__((ext_vector_type(8))) short short8v;
typedef __attribute__((ext_vector_type(4))) float float4v;

__device__ __forceinline__ float bf2f(ushort u) {
  union { unsigned int i; float f; } v;
  v.i = ((unsigned int)u) << 16;
  return v.f;
}
__device__ __forceinline__ ushort f2bf(float f) {
  union { float f; unsigned int i; } v;
  v.f = f;
  unsigned int b = v.i;
  return (ushort)((b + 0x7FFFu + ((b >> 16) & 1u)) >> 16);
}

// ---------------- zero init ----------------
__global__ __launch_bounds__(256) void k_zero(int* counts, float* linbuf, float* cbuf,
                                              ushort4* bfrag4, int N) {
  int i = blockIdx.x * 256 + threadIdx.x;
  if (i < N) counts[i] = 0;
  if (i < NOUT * HD) linbuf[i] = 0.f;
  if (i < NOUT) cbuf[i] = 0.f;
  if (i < NCHUNK * 3 * 64 * 2) bfrag4[i] = make_ushort4(0, 0, 0, 0);
}

__global__ __launch_bounds__(256) void k_count(const int* __restrict__ row, int* counts, int E) {
  int e = blockIdx.x * 256 + threadIdx.x;
  if (e < E) atomicAdd(&counts[row[e]], 1);
}

// ---------------- parallel scan (3 kernels) ----------------
__global__ __launch_bounds__(1024) void k_scan1(const int* __restrict__ counts, int* __restrict__ rowptr,
                                                int* __restrict__ bsum, int N) {
  __shared__ int sh[1024];
  int t = threadIdx.x, i = blockIdx.x * 1024 + t;
  int c = (i < N) ? counts[i] : 0;
  sh[t] = c;
  __syncthreads();
  for (int d = 1; d < 1024; d <<= 1) {
    int v = (t >= d) ? sh[t - d] : 0;
    __syncthreads();
    sh[t] += v;
    __syncthreads();
  }
  if (i < N) rowptr[i] = sh[t] - c;  // block-local exclusive
  if (t == 1023) bsum[blockIdx.x] = sh[1023];
}

__global__ __launch_bounds__(64) void k_scan2(const int* __restrict__ bsum, int* __restrict__ boff, int G) {
  int t = threadIdx.x;
  int base = 0;
  for (int s = 0; s < G; s += 64) {
    int i = s + t;
    int v = (i < G) ? bsum[i] : 0;
    int orig = v;
    for (int d = 1; d < 64; d <<= 1) {
      int u = __shfl_up(v, d, 64);
      if (t >= d) v += u;
    }
    if (i < G) boff[i] = base + v - orig;
    base += __shfl(v, 63, 64);
  }
}

__global__ __launch_bounds__(1024) void k_scan3(int* __restrict__ rowptr, int* __restrict__ cursor,
                                                const int* __restrict__ boff, int N, int E) {
  int i = blockIdx.x * 1024 + threadIdx.x;
  if (i < N) {
    int v = rowptr[i] + boff[blockIdx.x];
    rowptr[i] = v;
    cursor[i] = v;
  }
  if (i == 0) rowptr[N] = E;
}

__global__ __launch_bounds__(256) void k_fill(const int* __restrict__ row, const int* __restrict__ col,
                                              const float* __restrict__ w, int* cursor,
                                              int2* __restrict__ colw, int E) {
  int e = blockIdx.x * 256 + threadIdx.x;
  if (e < E) {
    int r = row[e];
    int p = atomicAdd(&cursor[r], 1);
    colw[p] = make_int2(col[e], __float_as_int(w[e]));
  }
}

// ---------------- W_in -> bf16 [64 cols][512 k], zero-padded ----------------
__global__ __launch_bounds__(256) void k_wcvt(const float* __restrict__ W, ushort* __restrict__ Wbf) {
  int i = blockIdx.x * 256 + threadIdx.x;
  if (i >= 64 * 512) return;
  int d = i >> 9, k = i & 511;
  Wbf[i] = (k < F_IN) ? f2bf(W[(size_t)k * HD + d]) : (ushort)0;
}

// ---------------- input GEMM via MFMA: h0 = relu(x @ W_in + b), bf16, 1 wave/block ----------------
__global__ __launch_bounds__(64) void k_gemm_in(const float* __restrict__ x,
                                                const ushort* __restrict__ Wbf,
                                                const float* __restrict__ b,
                                                ushort* __restrict__ h0bf, int N) {
  int lane = threadIdx.x;
  int c15 = lane & 15, g4 = lane >> 4;
  int rowA = blockIdx.x * 16 + c15;
  if (rowA >= N) rowA = N - 1;  // clamp; results discarded at store
  const float* xr = x + (size_t)rowA * F_IN;
  int koff = g4 * 8;
  float4v acc[4];
#pragma unroll
  for (int ct = 0; ct < 4; ++ct) acc[ct] = (float4v){0.f, 0.f, 0.f, 0.f};
#pragma unroll 5
  for (int kc = 0; kc < 15; ++kc) {
    int kbase = kc * 32 + koff;
    float4 f0 = *(const float4*)(xr + kbase);
    float4 f1 = *(const float4*)(xr + kbase + 4);
    short8v a;
    a[0] = (short)f2bf(f0.x); a[1] = (short)f2bf(f0.y);
    a[2] = (short)f2bf(f0.z); a[3] = (short)f2bf(f0.w);
    a[4] = (short)f2bf(f1.x); a[5] = (short)f2bf(f1.y);
    a[6] = (short)f2bf(f1.z); a[7] = (short)f2bf(f1.w);
#pragma unroll
    for (int ct = 0; ct < 4; ++ct) {
      const short8v bb = *(const short8v*)&Wbf[((ct * 16 + c15) << 9) + kbase];
      acc[ct] = __builtin_amdgcn_mfma_f32_16x16x32_bf16(a, bb, acc[ct], 0, 0, 0);
    }
  }
  {  // kc = 15 tail: floats 480..499 valid
    int kbase = 480 + koff;
    short8v a;
#pragma unroll
    for (int e = 0; e < 8; ++e) {
      int k = kbase + e;
      a[e] = (short)(k < F_IN ? f2bf(xr[k]) : (ushort)0);
    }
#pragma unroll
    for (int ct = 0; ct < 4; ++ct) {
      const short8v bb = *(const short8v*)&Wbf[((ct * 16 + c15) << 9) + kbase];
      acc[ct] = __builtin_amdgcn_mfma_f32_16x16x32_bf16(a, bb, acc[ct], 0, 0, 0);
    }
  }
  int mbase = blockIdx.x * 16 + g4 * 4;
#pragma unroll
  for (int ct = 0; ct < 4; ++ct) {
    int d = ct * 16 + c15;
    float bias = b[d];
#pragma unroll
    for (int r = 0; r < 4; ++r) {
      int m = mbase + r;
      if (m < N) {
        float v = acc[ct][r] + bias;
        h0bf[(size_t)m * HD + d] = f2bf(fmaxf(v, 0.f));
      }
    }
  }
}

// ---------------- GCN2 layer: gather (8-deep pipeline) + MFMA matvec, 32 rows/block ----------------
__global__ __launch_bounds__(256) void k_layer(const ushort* __restrict__ hin,
                                               const ushort* __restrict__ h0bf,
                                               const int* __restrict__ rowptr, const int2* __restrict__ colw,
                                               const float* __restrict__ convW, float beta,
                                               ushort* __restrict__ hout, int N) {
  __shared__ ushort mfrag[2][4][64][8];  // M=(1-b)I+bW in B-fragment layout, bf16, 8 KB
  __shared__ ushort sup[32][72];         // gathered sup rows, bf16 (+pad)
  __shared__ ushort outt[32][72];        // output tile
  __shared__ int2 ec[4][2][64];          // per-wave edge staging
  int tid = threadIdx.x, wv = tid >> 6, t = tid & 63;
  // phase 0: pack M fragments (each lane-frag: 8 values along k, fixed col)
  for (int f = tid; f < 512; f += 256) {
    int kc = f >> 8, ct = (f >> 6) & 3, ln = f & 63;
    int kb = kc * 32 + ((ln >> 4) << 3);
    int col = (ct << 4) + (ln & 15);
    short8v vals;
#pragma unroll
    for (int e = 0; e < 8; ++e) {
      int k = kb + e;
      float v = beta * convW[(k << 6) + col] + ((k == col) ? (1.f - beta) : 0.f);
      vals[e] = (short)f2bf(v);
    }
    *(short8v*)&mfrag[kc][ct][ln][0] = vals;
  }
  // phase 1: gather 8 rows per wave (2 interleaved at a time)
  int n0 = blockIdx.x * 32;
  for (int pr = 0; pr < 4; ++pr) {
    int rwA = wv * 8 + pr * 2, rwB = rwA + 1;
    int nA = n0 + rwA, nB = n0 + rwB;
    int e0A = 0, e1A = 0, e0B = 0, e1B = 0;
    if (nA < N) { e0A = rowptr[nA]; e1A = rowptr[nA + 1]; }
    if (nB < N) { e0B = rowptr[nB]; e1B = rowptr[nB + 1]; }
    int degA = e1A - e0A, degB = e1B - e0B;
    int degM = degA > degB ? degA : degB;
    float aA[4] = {0.f, 0.f, 0.f, 0.f}, aB[4] = {0.f, 0.f, 0.f, 0.f};
    for (int base = 0; base < degM; base += 64) {
      int rA = degA - base, rB = degB - base;
      ec[wv][0][t] = (t < rA) ? colw[e0A + base + t] : make_int2(0, 0);
      ec[wv][1][t] = (t < rB) ? colw[e0B + base + t] : make_int2(0, 0);
      int cA = rA < 0 ? 0 : (rA > 64 ? 64 : rA); cA = (cA + 7) & ~7;
      int cB = rB < 0 ? 0 : (rB > 64 ? 64 : rB); cB = (cB + 7) & ~7;
      int cM = cA > cB ? cA : cB;
      for (int j = 0; j < cM; j += 8) {
        if (j < cA) {
          int2 er[8];
#pragma unroll
          for (int k = 0; k < 8; ++k) er[k] = ec[wv][0][j + k];
          float g[8];
#pragma unroll
          for (int k = 0; k < 8; ++k) g[k] = bf2f(hin[(size_t)er[k].x * HD + t]);
#pragma unroll
          for (int k = 0; k < 8; ++k) aA[k & 3] = fmaf(__int_as_float(er[k].y), g[k], aA[k & 3]);
        }
        if (j < cB) {
          int2 er[8];
#pragma unroll
          for (int k = 0; k < 8; ++k) er[k] = ec[wv][1][j + k];
          float g[8];
#pragma unroll
          for (int k = 0; k < 8; ++k) g[k] = bf2f(hin[(size_t)er[k].x * HD + t]);
#pragma unroll
          for (int k = 0; k < 8; ++k) aB[k & 3] = fmaf(__int_as_float(er[k].y), g[k], aB[k & 3]);
        }
      }
    }
    if (nA < N) {
      float s = 0.9f * ((aA[0] + aA[1]) + (aA[2] + aA[3])) + 0.1f * bf2f(h0bf[(size_t)nA * HD + t]);
      sup[rwA][t] = f2bf(s);
    } else sup[rwA][t] = 0;
    if (nB < N) {
      float s = 0.9f * ((aB[0] + aB[1]) + (aB[2] + aB[3])) + 0.1f * bf2f(h0bf[(size_t)nB * HD + t]);
      sup[rwB][t] = f2bf(s);
    } else sup[rwB][t] = 0;
  }
  __syncthreads();
  // phase 2: out = relu(sup @ M) via MFMA. wave -> (row-tile, col-pair)
  {
    int rt = wv >> 1, cp = (wv & 1) * 2;
    const short8v a0 = *(const short8v*)&sup[rt * 16 + (t & 15)][(t >> 4) * 8];
    const short8v a1 = *(const short8v*)&sup[rt * 16 + (t & 15)][32 + (t >> 4) * 8];
#pragma unroll
    for (int q = 0; q < 2; ++q) {
      int ct = cp + q;
      const short8v b0 = *(const short8v*)&mfrag[0][ct][t][0];
      const short8v b1 = *(const short8v*)&mfrag[1][ct][t][0];
      float4v acc = (float4v){0.f, 0.f, 0.f, 0.f};
      acc = __builtin_amdgcn_mfma_f32_16x16x32_bf16(a0, b0, acc, 0, 0, 0);
      acc = __builtin_amdgcn_mfma_f32_16x16x32_bf16(a1, b1, acc, 0, 0, 0);
#pragma unroll
      for (int r = 0; r < 4; ++r) {
        int row = rt * 16 + (t >> 4) * 4 + r;
        outt[row][ct * 16 + (t & 15)] = f2bf(fmaxf(acc[r], 0.f));
      }
    }
  }
  __syncthreads();
  // phase 3: coalesced store (32 rows x 64 cols bf16)
  {
    int row = tid >> 3, c0 = (tid & 7) * 8;
    int n = n0 + row;
    if (n < N) *(short8v*)&hout[(size_t)n * HD + c0] = *(const short8v*)&outt[row][c0];
  }
}

// ---------------- group table: g -> (m, l0) ----------------
__global__ __launch_bounds__(512) void k_gtab(int2* __restrict__ gtab) {
  int g = threadIdx.x;
  if (g >= NGRP) return;
  int m = 64, l0 = 65;
  if (g < 297) {
    int cum = 0;
    for (int mm = 0; mm < 65; ++mm) {
      int ng = (65 - mm + 7) >> 3;
      if (g < cum + ng) { m = mm; l0 = mm + (g - cum) * 8; break; }
      cum += ng;
    }
  }
  gtab[g] = make_int2(m, l0);
}

// ---------------- T[r,o] = Wo_o @ V_r^T  (+ linear/const bias terms) ----------------
__global__ __launch_bounds__(256) void k_T(const float* __restrict__ W_out, const float* __restrict__ V_W,
                                           const float* __restrict__ V_b, const float* __restrict__ U_W,
                                           const float* __restrict__ U_b,
                                           float* __restrict__ Tbuf, float* linbuf, float* cbuf) {
  int o = blockIdx.x % NOUT;
  int r = blockIdx.x / NOUT;
  __shared__ float Wo[64][65];
  __shared__ float Vs[64][65];
  __shared__ float t1[64], t2[64];
  int tid = threadIdx.x;
  int tx = tid & 15, ty = tid >> 4;
  for (int idx = tid; idx < 4096; idx += 256) {
    int m = idx >> 6, l = idx & 63;
    Wo[m][l] = W_out[(size_t)idx * NOUT + o];
    Vs[m][l] = V_W[(size_t)(r * 64 + m) * 64 + l];
  }
  __syncthreads();
  float acc[4][4] = {};
  for (int l = 0; l < 64; ++l) {
    float av[4], bv[4];
#pragma unroll
    for (int i = 0; i < 4; ++i) av[i] = Wo[ty * 4 + i][l];
#pragma unroll
    for (int j = 0; j < 4; ++j) bv[j] = Vs[tx * 4 + j][l];
#pragma unroll
    for (int i = 0; i < 4; ++i)
#pragma unroll
      for (int j = 0; j < 4; ++j) acc[i][j] = fmaf(av[i], bv[j], acc[i][j]);
  }
#pragma unroll
  for (int i = 0; i < 4; ++i)
#pragma unroll
    for (int j = 0; j < 4; ++j)
      Tbuf[(((size_t)r * NOUT + o) * 64 + ty * 4 + i) * 64 + tx * 4 + j] = acc[i][j];
  if (tid < 64) {
    float s1 = 0.f, s2 = 0.f;
    for (int l = 0; l < 64; ++l) s1 = fmaf(Wo[tid][l], V_b[r * 64 + l], s1);
    for (int m = 0; m < 64; ++m) s2 = fmaf(Wo[m][tid], U_b[r * 64 + m], s2);
    t1[tid] = s1;
    t2[tid] = s2;
  }
  __syncthreads();
  if (tid < 64) {
    float s = 0.f, s2 = 0.f;
    for (int m = 0; m < 64; ++m) s = fmaf(U_W[(size_t)(r * 64 + tid) * 64 + m], t1[m], s);
    for (int l = 0; l < 64; ++l) s2 = fmaf(Vs[tid][l], t2[l], s2);
    atomicAdd(&linbuf[o * 64 + tid], s + s2);
  }
  if (tid == 0) {
    float s = 0.f;
    for (int m = 0; m < 64; ++m) s = fmaf(U_b[r * 64 + m], t1[m], s);
    atomicAdd(&cbuf[o], s);
  }
}

// ---------------- Q_o = sum_r U_r @ T[r,o]; pack bf16 B-fragments ----------------
__global__ __launch_bounds__(256) void k_Q(const float* __restrict__ U_W, const float* __restrict__ Tbuf,
                                           const float* __restrict__ linbuf, const float* __restrict__ cbuf,
                                           const float* __restrict__ b_out,
                                           const int2* __restrict__ gtab, ushort* __restrict__ Bfrag) {
  int o = blockIdx.x;
  __shared__ float Us[64][65];
  __shared__ float Tb[64][65];
  __shared__ float Q[64][65];
  int tid = threadIdx.x, tx = tid & 15, ty = tid >> 4;
  float acc[4][4] = {};
  for (int r = 0; r < NRANK; ++r) {
    for (int idx = tid; idx < 4096; idx += 256) {
      int a = idx >> 6, mm = idx & 63;
      Us[a][mm] = U_W[(size_t)(r * 64 + a) * 64 + mm];
      Tb[a][mm] = Tbuf[(((size_t)r * NOUT + o) * 64 + a) * 64 + mm];
    }
    __syncthreads();
    for (int mm = 0; mm < 64; ++mm) {
      float av[4], bv[4];
#pragma unroll
      for (int i = 0; i < 4; ++i) av[i] = Us[ty * 4 + i][mm];
#pragma unroll
      for (int j = 0; j < 4; ++j) bv[j] = Tb[mm][tx * 4 + j];
#pragma unroll
      for (int i = 0; i < 4; ++i)
#pragma unroll
        for (int j = 0; j < 4; ++j) acc[i][j] = fmaf(av[i], bv[j], acc[i][j]);
    }
    __syncthreads();
  }
#pragma unroll
  for (int i = 0; i < 4; ++i)
#pragma unroll
    for (int j = 0; j < 4; ++j) Q[ty * 4 + i][tx * 4 + j] = acc[i][j];
  __syncthreads();
  int ot = o >> 4, o15 = o & 15;
  for (int idx = tid; idx < NGRP * 8; idx += 256) {
    int g = idx >> 3, e = idx & 7;
    int2 ml = gtab[g];
    int m = ml.x, l = ml.y + e;
    float v;
    if (l < 64) v = (m == l) ? Q[m][m] : Q[m][l] + Q[l][m];
    else if (l == 64) v = (m == 64) ? (cbuf[o] + b_out[o]) : linbuf[o * 64 + m];
    else v = 0.f;
    int c = g >> 2, g4 = g & 3;
    Bfrag[((((size_t)c * 3 + ot) * 64) + g4 * 16 + o15) * 8 + e] = f2bf(v);
  }
}

// ---------------- logits via MFMA + fused expmap0/proj/log_softmax ----------------
__global__ __launch_bounds__(256) void k_logits(const ushort* __restrict__ hbf,
                                                const ushort* __restrict__ Bfrag,
                                                const int2* __restrict__ gtab,
                                                float* __restrict__ out, int N) {
  __shared__ float eh[128][77];
  __shared__ int2 gs[NGRP];
  int tid = threadIdx.x;
  int n0 = blockIdx.x * 128;
  for (int idx = tid; idx < 128 * 16; idx += 256) {
    int n = idx >> 4, f4 = (idx & 15) << 2;
    int gn = n0 + n;
    float v0 = 0.f, v1 = 0.f, v2 = 0.f, v3 = 0.f;
    if (gn < N) {
      ushort4 u = *(const ushort4*)&hbf[(size_t)gn * HD + f4];
      v0 = bf2f(u.x); v1 = bf2f(u.y); v2 = bf2f(u.z); v3 = bf2f(u.w);
    }
    eh[n][f4] = v0; eh[n][f4 + 1] = v1; eh[n][f4 + 2] = v2; eh[n][f4 + 3] = v3;
  }
  for (int idx = tid; idx < 128 * 13; idx += 256) {
    int n = idx / 13, j = idx - n * 13;
    eh[n][64 + j] = (j == 0) ? 1.f : 0.f;
  }
  for (int idx = tid; idx < NGRP; idx += 256) gs[idx] = gtab[idx];
  __syncthreads();

  int w = tid >> 6, lane = tid & 63;
  int g4 = lane >> 4, c15 = lane & 15;
  float4v acc[2][3];
#pragma unroll
  for (int t = 0; t < 2; ++t)
#pragma unroll
    for (int ot = 0; ot < 3; ++ot) acc[t][ot] = (float4v){0.f, 0.f, 0.f, 0.f};
  const float* ehr0 = &eh[(w * 2 + 0) * 16 + c15][0];
  const float* ehr1 = &eh[(w * 2 + 1) * 16 + c15][0];

  for (int c = 0; c < NCHUNK; ++c) {
    const short8v b0 = *(const short8v*)&Bfrag[(((size_t)c * 3 + 0) * 64 + lane) * 8];
    const short8v b1 = *(const short8v*)&Bfrag[(((size_t)c * 3 + 1) * 64 + lane) * 8];
    const short8v b2 = *(const short8v*)&Bfrag[(((size_t)c * 3 + 2) * 64 + lane) * 8];
    int2 ml = gs[c * 4 + g4];
    int m = ml.x, l0 = ml.y;
    float hm0 = ehr0[m], hm1 = ehr1[m];
    short8v a0, a1;
#pragma unroll
    for (int e = 0; e < 8; ++e) {
      a0[e] = (short)f2bf(hm0 * ehr0[l0 + e]);
      a1[e] = (short)f2bf(hm1 * ehr1[l0 + e]);
    }
    acc[0][0] = __builtin_amdgcn_mfma_f32_16x16x32_bf16(a0, b0, acc[0][0], 0, 0, 0);
    acc[1][0] = __builtin_amdgcn_mfma_f32_16x16x32_bf16(a1, b0, acc[1][0], 0, 0, 0);
    acc[0][1] = __builtin_amdgcn_mfma_f32_16x16x32_bf16(a0, b1, acc[0][1], 0, 0, 0);
    acc[1][1] = __builtin_amdgcn_mfma_f32_16x16x32_bf16(a1, b1, acc[1][1], 0, 0, 0);
    acc[0][2] = __builtin_amdgcn_mfma_f32_16x16x32_bf16(a0, b2, acc[0][2], 0, 0, 0);
    acc[1][2] = __builtin_amdgcn_mfma_f32_16x16x32_bf16(a1, b2, acc[1][2], 0, 0, 0);
  }

  __syncthreads();  // all eh reads done; reuse as logits tile [128][41]
  float* ls = &eh[0][0];
#pragma unroll
  for (int t = 0; t < 2; ++t) {
    int rbase = (w * 2 + t) * 16 + g4 * 4;
#pragma unroll
    for (int ot = 0; ot < 3; ++ot) {
      int o = ot * 16 + c15;
      if (o < NOUT) {
#pragma unroll
        for (int r = 0; r < 4; ++r) ls[(rbase + r) * 41 + o] = acc[t][ot][r];
      }
    }
  }
  __syncthreads();
  if (tid < 128) {
    int n = n0 + tid;
    if (n < N) {
      float v[40];
      float s = 0.f;
#pragma unroll
      for (int i = 0; i < 40; ++i) { v[i] = ls[tid * 41 + i]; s = fmaf(v[i], v[i], s); }
      float un = fmaxf(sqrtf(s), 1e-15f);
      float sc = tanhf(un) / un;
      float s2 = 0.f;
#pragma unroll
      for (int i = 0; i < 40; ++i) { v[i] *= sc; s2 = fmaf(v[i], v[i], s2); }
      float ny = fmaxf(sqrtf(s2), 1e-15f);
      float maxn = 1.0f - 4e-3f;
      if (ny > maxn) {
        float f = maxn / ny;
#pragma unroll
        for (int i = 0; i < 40; ++i) v[i] *= f;
      }
      float vmax = v[0];
#pragma unroll
      for (int i = 1; i < 40; ++i) vmax = fmaxf(vmax, v[i]);
      float se = 0.f;
#pragma unroll
      for (int i = 0; i < 40; ++i) se += expf(v[i] - vmax);
      float lse = logf(se) + vmax;
      float4* q = (float4*)(out + (size_t)n * NOUT);
#pragma unroll
      for (int i = 0; i < 10; ++i) {
        float4 t;
        t.x = v[4 * i] - lse;
        t.y = v[4 * i + 1] - lse;
        t.z = v[4 * i + 2] - lse;
        t.w = v[4 * i + 3] - lse;
        q[i] = t;
      }
    }
  }
}

extern "C" void kernel_launch(void* const* d_in, const int* in_sizes, int n_in,
                              void* d_out, int out_size, void* d_ws, size_t ws_size,
                              hipStream_t stream) {
  const float* x = (const float*)d_in[0];
  const int* erow = (const int*)d_in[1];
  const int* ecol = (const int*)d_in[2];
  const float* ew = (const float*)d_in[3];
  const float* W_in = (const float*)d_in[4];
  const float* b_in = (const float*)d_in[5];
  const float* conv_W = (const float*)d_in[6];
  const float* U_W = (const float*)d_in[7];
  const float* U_b = (const float*)d_in[8];
  const float* V_W = (const float*)d_in[9];
  const float* V_b = (const float*)d_in[10];
  const float* W_out = (const float*)d_in[11];
  const float* b_out = (const float*)d_in[12];
  int N = in_sizes[0] / F_IN;
  int E = in_sizes[1];
  float* out = (float*)d_out;

  char* base = (char*)d_ws;
  size_t off = 0;
  auto alloc = [&](size_t bytes) -> void* {
    void* p = base + off;
    off += (bytes + 255) & ~(size_t)255;
    return p;
  };
  ushort* h0bf = (ushort*)alloc((size_t)N * HD * 2);
  ushort* hbfA = (ushort*)alloc((size_t)N * HD * 2);
  ushort* hbfB = (ushort*)alloc((size_t)N * HD * 2);
  int* rowptr = (int*)alloc((size_t)(N + 1) * 4);
  int* cursor = (int*)alloc((size_t)N * 4);
  int* counts = (int*)alloc((size_t)N * 4);
  int2* colw = (int2*)alloc((size_t)E * 8);
  float* Tbuf = (float*)alloc((size_t)NRANK * NOUT * 64 * 64 * 4);
  ushort* Bfrag = (ushort*)alloc((size_t)NCHUNK * 3 * 64 * 8 * 2);
  ushort* Wbf = (ushort*)alloc((size_t)64 * 512 * 2);
  float* linbuf = (float*)alloc(NOUT * 64 * 4);
  float* cbuf = (float*)alloc(NOUT * 4);
  int2* gtab = (int2*)alloc(NGRP * 8);
  int* bsum = (int*)alloc(64 * 4);
  int* boff = (int*)alloc(64 * 4);

  int G = (N + 1023) / 1024;

  k_zero<<<(N + 255) / 256, 256, 0, stream>>>(counts, linbuf, cbuf, (ushort4*)Bfrag, N);
  k_count<<<(E + 255) / 256, 256, 0, stream>>>(erow, counts, E);
  k_scan1<<<G, 1024, 0, stream>>>(counts, rowptr, bsum, N);
  k_scan2<<<1, 64, 0, stream>>>(bsum, boff, G);
  k_scan3<<<G, 1024, 0, stream>>>(rowptr, cursor, boff, N, E);
  k_fill<<<(E + 255) / 256, 256, 0, stream>>>(erow, ecol, ew, cursor, colw, E);
  k_wcvt<<<128, 256, 0, stream>>>(W_in, Wbf);
  k_gemm_in<<<(N + 15) / 16, 64, 0, stream>>>(x, Wbf, b_in, h0bf, N);
  k_gtab<<<1, 512, 0, stream>>>(gtab);
  k_T<<<NRANK * NOUT, 256, 0, stream>>>(W_out, V_W, V_b, U_W, U_b, Tbuf, linbuf, cbuf);
  k_Q<<<NOUT, 256, 0, stream>>>(U_W, Tbuf, linbuf, cbuf, b_out, gtab, Bfrag);

  const ushort* hin = h0bf;
  ushort* hout = hbfA;
  for (int l = 0; l < NL; ++l) {
    float beta = (float)std::log(0.5 / (double)(l + 1) + 1.0);
    k_layer<<<(N + 31) / 32, 256, 0, stream>>>(hin, h0bf, rowptr, colw,
                                               conv_W + (size_t)l * HD * HD,
                                               beta, hout, N);
    hin = hout;
    hout = (hout == hbfA) ? hbfB : hbfA;
  }
  k_logits<<<(N + 127) / 128, 256, 0, stream>>>(hin, Bfrag, gtab, out, N);
}

// Round 7
// 528.046 us; speedup vs baseline: 1.0066x; 1.0019x over previous
//
#include <hip/hip_runtime.h>
#include <cmath>

#define F_IN 500
#define HD 64
#define NL 8
#define NRANK 3
#define NOUT 40
#define NGRP 300   // 297 real (m,l0) groups of 8 + 3 zero pads -> K = 2400
#define NCHUNK 75  // 2400 / 32

typedef __attribute__((ext_vector_type(8))) short short8v;
typedef __attribute__((ext_vector_type(4))) float float4v;

__device__ __forceinline__ float bf2f(ushort u) {
  union { unsigned int i; float f; } v;
  v.i = ((unsigned int)u) << 16;
  return v.f;
}
__device__ __forceinline__ ushort f2bf(float f) {
  union { float f; unsigned int i; } v;
  v.f = f;
  unsigned int b = v.i;
  return (ushort)((b + 0x7FFFu + ((b >> 16) & 1u)) >> 16);
}

__device__ __forceinline__ void dma16(const void* g, void* l) {
  __builtin_amdgcn_global_load_lds((const __attribute__((address_space(1))) void*)g,
                                   (__attribute__((address_space(3))) void*)l, 16, 0, 0);
}

// ---------------- zero init (counts, bias bufs, Bfrag, padded colw) ----------------
__global__ __launch_bounds__(256) void k_zero(int* counts, float* linbuf, float* cbuf,
                                              ushort4* bfrag4, int2* colw, int epad, int N) {
  int i = blockIdx.x * 256 + threadIdx.x;
  if (i < N) counts[i] = 0;
  if (i < NOUT * HD) linbuf[i] = 0.f;
  if (i < NOUT) cbuf[i] = 0.f;
  if (i < NCHUNK * 3 * 64 * 2) bfrag4[i] = make_ushort4(0, 0, 0, 0);
  for (int j = i; j < epad; j += gridDim.x * 256) colw[j] = make_int2(0, 0);
}

__global__ __launch_bounds__(256) void k_count(const int* __restrict__ row, int* counts, int E) {
  int e = blockIdx.x * 256 + threadIdx.x;
  if (e < E) atomicAdd(&counts[row[e]], 1);
}

// ---------------- parallel scan over PADDED degrees (3 kernels) ----------------
__global__ __launch_bounds__(1024) void k_scan1(const int* __restrict__ counts, int* __restrict__ rowptr,
                                                int* __restrict__ bsum, int N) {
  __shared__ int sh[1024];
  int t = threadIdx.x, i = blockIdx.x * 1024 + t;
  int c = (i < N) ? ((counts[i] + 7) & ~7) : 0;
  sh[t] = c;
  __syncthreads();
  for (int d = 1; d < 1024; d <<= 1) {
    int v = (t >= d) ? sh[t - d] : 0;
    __syncthreads();
    sh[t] += v;
    __syncthreads();
  }
  if (i < N) rowptr[i] = sh[t] - c;  // block-local exclusive
  if (t == 1023) bsum[blockIdx.x] = sh[1023];
}

__global__ __launch_bounds__(64) void k_scan2(const int* __restrict__ bsum, int* __restrict__ boff, int G) {
  int t = threadIdx.x;
  int base = 0;
  for (int s = 0; s < G; s += 64) {
    int i = s + t;
    int v = (i < G) ? bsum[i] : 0;
    int orig = v;
    for (int d = 1; d < 64; d <<= 1) {
      int u = __shfl_up(v, d, 64);
      if (t >= d) v += u;
    }
    if (i < G) boff[i] = base + v - orig;
    base += __shfl(v, 63, 64);
  }
}

__global__ __launch_bounds__(1024) void k_scan3(int* __restrict__ rowptr, int* __restrict__ cursor,
                                                const int* __restrict__ boff,
                                                const int* __restrict__ counts, int N) {
  int i = blockIdx.x * 1024 + threadIdx.x;
  if (i < N) {
    int v = rowptr[i] + boff[blockIdx.x];
    rowptr[i] = v;
    cursor[i] = v;
    if (i == N - 1) rowptr[N] = v + ((counts[i] + 7) & ~7);
  }
}

__global__ __launch_bounds__(256) void k_fill(const int* __restrict__ row, const int* __restrict__ col,
                                              const float* __restrict__ w, int* cursor,
                                              int2* __restrict__ colw, int E) {
  int e = blockIdx.x * 256 + threadIdx.x;
  if (e < E) {
    int r = row[e];
    int p = atomicAdd(&cursor[r], 1);
    colw[p] = make_int2(col[e] * HD, __float_as_int(w[e]));  // pre-scaled col offset
  }
}

// ---------------- W_in -> bf16 [64 cols][512 k], zero-padded ----------------
__global__ __launch_bounds__(256) void k_wcvt(const float* __restrict__ W, ushort* __restrict__ Wbf) {
  int i = blockIdx.x * 256 + threadIdx.x;
  if (i >= 64 * 512) return;
  int d = i >> 9, k = i & 511;
  Wbf[i] = (k < F_IN) ? f2bf(W[(size_t)k * HD + d]) : (ushort)0;
}

// ---------------- input GEMM via MFMA + global_load_lds double-buffered staging ----------------
// 64 rows/block, K chunks of 64 f32. LDS layout: 16 groups of (4 rows x 64 f32) + 8-float pad.
__global__ __launch_bounds__(256) void k_gemm_in(const float* __restrict__ x,
                                                 const ushort* __restrict__ Wbf,
                                                 const float* __restrict__ b,
                                                 ushort* __restrict__ h0bf, int N) {
  __shared__ float xs[2][16 * 264];
  int tid = threadIdx.x;
  int w = tid >> 6, lane = tid & 63;
  int c15 = lane & 15, g4 = lane >> 4;
  int n0 = blockIdx.x * 64;
  const float* xlim = x + (size_t)N * F_IN - 4;

  auto stage = [&](int c, int bsel) {
#pragma unroll
    for (int i = 0; i < 4; ++i) {
      int grp = w * 4 + i;
      int row = n0 + grp * 4 + (lane >> 4);
      if (row > N - 1) row = N - 1;
      const float* src = x + (size_t)row * F_IN + c * 64 + (lane & 15) * 4;
      if (src > xlim) src = xlim;
      dma16(src, &xs[bsel][grp * 264]);
    }
  };

  float4v acc[4];
#pragma unroll
  for (int ct = 0; ct < 4; ++ct) acc[ct] = (float4v){0.f, 0.f, 0.f, 0.f};

  stage(0, 0);
  __syncthreads();
  int buf = 0;
  int grp = w * 4 + (c15 >> 2), sub = c15 & 3;
  int fbase = grp * 264 + sub * 64;
  for (int c = 0; c < 8; ++c) {
    if (c < 7) stage(c + 1, buf ^ 1);
#pragma unroll
    for (int s = 0; s < 2; ++s) {
      int off = fbase + s * 32 + g4 * 8;
      float4 fa = *(const float4*)&xs[buf][off];
      float4 fb = *(const float4*)&xs[buf][off + 4];
      short8v a;
      a[0] = (short)f2bf(fa.x); a[1] = (short)f2bf(fa.y);
      a[2] = (short)f2bf(fa.z); a[3] = (short)f2bf(fa.w);
      a[4] = (short)f2bf(fb.x); a[5] = (short)f2bf(fb.y);
      a[6] = (short)f2bf(fb.z); a[7] = (short)f2bf(fb.w);
      int kbase = c * 64 + s * 32 + g4 * 8;
#pragma unroll
      for (int ct = 0; ct < 4; ++ct) {
        const short8v bb = *(const short8v*)&Wbf[((ct * 16 + c15) << 9) + kbase];
        acc[ct] = __builtin_amdgcn_mfma_f32_16x16x32_bf16(a, bb, acc[ct], 0, 0, 0);
      }
    }
    __syncthreads();  // drains DMA vmcnt; buf^1 ready, all reads of buf done
    buf ^= 1;
  }
  int mbase = n0 + w * 16 + g4 * 4;
#pragma unroll
  for (int ct = 0; ct < 4; ++ct) {
    int d = ct * 16 + c15;
    float bias = b[d];
#pragma unroll
    for (int r = 0; r < 4; ++r) {
      int m = mbase + r;
      if (m < N) {
        float v = acc[ct][r] + bias;
        h0bf[(size_t)m * HD + d] = f2bf(fmaxf(v, 0.f));
      }
    }
  }
}

// ---------------- per-layer matvec matrix in MFMA B-frag layout (once per layer) ----------------
__global__ __launch_bounds__(256) void k_mpack(const float* __restrict__ conv_W, ushort* __restrict__ Mfrag) {
  int l = blockIdx.x;
  const float* convW = conv_W + (size_t)l * HD * HD;
  ushort* out = Mfrag + (size_t)l * 512 * 8;
  float beta = logf(0.5f / (float)(l + 1) + 1.0f);
  int tid = threadIdx.x;
  for (int f = tid; f < 512; f += 256) {
    int kc = f >> 8, ct = (f >> 6) & 3, ln = f & 63;
    int kb = kc * 32 + ((ln >> 4) << 3);
    int col = (ct << 4) + (ln & 15);
    short8v vals;
#pragma unroll
    for (int e = 0; e < 8; ++e) {
      int k = kb + e;
      float v = beta * convW[(k << 6) + col] + ((k == col) ? (1.f - beta) : 0.f);
      vals[e] = (short)f2bf(v);
    }
    *(short8v*)&out[(size_t)f * 8] = vals;
  }
}

// ---------------- GCN2 layer: direct-load padded-CSR gather + MFMA matvec, 32 rows/block ----------------
__global__ __launch_bounds__(256) void k_layer(const ushort* __restrict__ hin,
                                               const ushort* __restrict__ h0bf,
                                               const int* __restrict__ rowptrP, const int2* __restrict__ colw,
                                               const ushort* __restrict__ MfragL,
                                               ushort* __restrict__ hout, int N) {
  __shared__ ushort mfrag[512][8];
  __shared__ ushort sup[32][72];
  __shared__ ushort outt[32][72];
  int tid = threadIdx.x, wv = tid >> 6, t = tid & 63;
  {  // coalesced mfrag load (8 KB)
    const short8v* src = (const short8v*)MfragL;
    short8v* dst = (short8v*)&mfrag[0][0];
    dst[tid] = src[tid];
    dst[tid + 256] = src[tid + 256];
  }
  int n0 = blockIdx.x * 32;
  int base_row = n0 + wv * 8;
  int re = 0;
  if (t < 9) {
    int nn = base_row + t;
    if (nn <= N) re = rowptrP[nn];
  }
  const int4* cw4 = (const int4*)colw;
  for (int rr = 0; rr < 8; ++rr) {
    int rw = wv * 8 + rr;
    int n = n0 + rw;
    if (n < N) {
      int j = __shfl(re, rr, 64);
      int je = __shfl(re, rr + 1, 64);
      float acc0 = 0.f, acc1 = 0.f;
      if (j < je) {
        int4 q0 = cw4[(j >> 1)], q1 = cw4[(j >> 1) + 1];
        int4 q2 = cw4[(j >> 1) + 2], q3 = cw4[(j >> 1) + 3];
        j += 8;
        for (;;) {
          // 8 gathers issued back-to-back
          float g0 = bf2f(hin[(size_t)(unsigned)q0.x + t]);
          float g1 = bf2f(hin[(size_t)(unsigned)q0.z + t]);
          float g2 = bf2f(hin[(size_t)(unsigned)q1.x + t]);
          float g3 = bf2f(hin[(size_t)(unsigned)q1.z + t]);
          float g4_ = bf2f(hin[(size_t)(unsigned)q2.x + t]);
          float g5 = bf2f(hin[(size_t)(unsigned)q2.z + t]);
          float g6 = bf2f(hin[(size_t)(unsigned)q3.x + t]);
          float g7 = bf2f(hin[(size_t)(unsigned)q3.z + t]);
          bool more = j < je;
          int4 p0, p1, p2, p3;
          if (more) {  // prefetch next edge batch while gathers are in flight
            p0 = cw4[(j >> 1)]; p1 = cw4[(j >> 1) + 1];
            p2 = cw4[(j >> 1) + 2]; p3 = cw4[(j >> 1) + 3];
          }
          acc0 = fmaf(__int_as_float(q0.y), g0, acc0);
          acc1 = fmaf(__int_as_float(q0.w), g1, acc1);
          acc0 = fmaf(__int_as_float(q1.y), g2, acc0);
          acc1 = fmaf(__int_as_float(q1.w), g3, acc1);
          acc0 = fmaf(__int_as_float(q2.y), g4_, acc0);
          acc1 = fmaf(__int_as_float(q2.w), g5, acc1);
          acc0 = fmaf(__int_as_float(q3.y), g6, acc0);
          acc1 = fmaf(__int_as_float(q3.w), g7, acc1);
          if (!more) break;
          q0 = p0; q1 = p1; q2 = p2; q3 = p3;
          j += 8;
        }
      }
      float s = 0.9f * (acc0 + acc1) + 0.1f * bf2f(h0bf[(size_t)n * HD + t]);
      sup[rw][t] = f2bf(s);
    } else {
      sup[rw][t] = 0;
    }
  }
  __syncthreads();
  // matvec: out = relu(sup @ M) via MFMA
  {
    int rt = wv >> 1, cp = (wv & 1) * 2;
    int c15 = t & 15, g4i = t >> 4;
    const short8v a0 = *(const short8v*)&sup[rt * 16 + c15][g4i * 8];
    const short8v a1 = *(const short8v*)&sup[rt * 16 + c15][32 + g4i * 8];
#pragma unroll
    for (int q = 0; q < 2; ++q) {
      int ct = cp + q;
      const short8v b0 = *(const short8v*)&mfrag[ct * 64 + t][0];
      const short8v b1 = *(const short8v*)&mfrag[256 + ct * 64 + t][0];
      float4v acc = (float4v){0.f, 0.f, 0.f, 0.f};
      acc = __builtin_amdgcn_mfma_f32_16x16x32_bf16(a0, b0, acc, 0, 0, 0);
      acc = __builtin_amdgcn_mfma_f32_16x16x32_bf16(a1, b1, acc, 0, 0, 0);
#pragma unroll
      for (int r = 0; r < 4; ++r) {
        int row = rt * 16 + g4i * 4 + r;
        outt[row][ct * 16 + c15] = f2bf(fmaxf(acc[r], 0.f));
      }
    }
  }
  __syncthreads();
  {
    int row = tid >> 3, c0 = (tid & 7) * 8;
    int n = n0 + row;
    if (n < N) *(short8v*)&hout[(size_t)n * HD + c0] = *(const short8v*)&outt[row][c0];
  }
}

// ---------------- group table: g -> (m, l0) ----------------
__global__ __launch_bounds__(512) void k_gtab(int2* __restrict__ gtab) {
  int g = threadIdx.x;
  if (g >= NGRP) return;
  int m = 64, l0 = 65;
  if (g < 297) {
    int cum = 0;
    for (int mm = 0; mm < 65; ++mm) {
      int ng = (65 - mm + 7) >> 3;
      if (g < cum + ng) { m = mm; l0 = mm + (g - cum) * 8; break; }
      cum += ng;
    }
  }
  gtab[g] = make_int2(m, l0);
}

// ---------------- T[r,o] = Wo_o @ V_r^T  (+ linear/const bias terms) ----------------
__global__ __launch_bounds__(256) void k_T(const float* __restrict__ W_out, const float* __restrict__ V_W,
                                           const float* __restrict__ V_b, const float* __restrict__ U_W,
                                           const float* __restrict__ U_b,
                                           float* __restrict__ Tbuf, float* linbuf, float* cbuf) {
  int o = blockIdx.x % NOUT;
  int r = blockIdx.x / NOUT;
  __shared__ float Wo[64][65];
  __shared__ float Vs[64][65];
  __shared__ float t1[64], t2[64];
  int tid = threadIdx.x;
  int tx = tid & 15, ty = tid >> 4;
  for (int idx = tid; idx < 4096; idx += 256) {
    int m = idx >> 6, l = idx & 63;
    Wo[m][l] = W_out[(size_t)idx * NOUT + o];
    Vs[m][l] = V_W[(size_t)(r * 64 + m) * 64 + l];
  }
  __syncthreads();
  float acc[4][4] = {};
  for (int l = 0; l < 64; ++l) {
    float av[4], bv[4];
#pragma unroll
    for (int i = 0; i < 4; ++i) av[i] = Wo[ty * 4 + i][l];
#pragma unroll
    for (int j = 0; j < 4; ++j) bv[j] = Vs[tx * 4 + j][l];
#pragma unroll
    for (int i = 0; i < 4; ++i)
#pragma unroll
      for (int j = 0; j < 4; ++j) acc[i][j] = fmaf(av[i], bv[j], acc[i][j]);
  }
#pragma unroll
  for (int i = 0; i < 4; ++i)
#pragma unroll
    for (int j = 0; j < 4; ++j)
      Tbuf[(((size_t)r * NOUT + o) * 64 + ty * 4 + i) * 64 + tx * 4 + j] = acc[i][j];
  if (tid < 64) {
    float s1 = 0.f, s2 = 0.f;
    for (int l = 0; l < 64; ++l) s1 = fmaf(Wo[tid][l], V_b[r * 64 + l], s1);
    for (int m = 0; m < 64; ++m) s2 = fmaf(Wo[m][tid], U_b[r * 64 + m], s2);
    t1[tid] = s1;
    t2[tid] = s2;
  }
  __syncthreads();
  if (tid < 64) {
    float s = 0.f, s2 = 0.f;
    for (int m = 0; m < 64; ++m) s = fmaf(U_W[(size_t)(r * 64 + tid) * 64 + m], t1[m], s);
    for (int l = 0; l < 64; ++l) s2 = fmaf(Vs[tid][l], t2[l], s2);
    atomicAdd(&linbuf[o * 64 + tid], s + s2);
  }
  if (tid == 0) {
    float s = 0.f;
    for (int m = 0; m < 64; ++m) s = fmaf(U_b[r * 64 + m], t1[m], s);
    atomicAdd(&cbuf[o], s);
  }
}

// ---------------- Q_o = sum_r U_r @ T[r,o]; pack bf16 B-fragments ----------------
__global__ __launch_bounds__(256) void k_Q(const float* __restrict__ U_W, const float* __restrict__ Tbuf,
                                           const float* __restrict__ linbuf, const float* __restrict__ cbuf,
                                           const float* __restrict__ b_out,
                                           const int2* __restrict__ gtab, ushort* __restrict__ Bfrag) {
  int o = blockIdx.x;
  __shared__ float Us[64][65];
  __shared__ float Tb[64][65];
  __shared__ float Q[64][65];
  int tid = threadIdx.x, tx = tid & 15, ty = tid >> 4;
  float acc[4][4] = {};
  for (int r = 0; r < NRANK; ++r) {
    for (int idx = tid; idx < 4096; idx += 256) {
      int a = idx >> 6, mm = idx & 63;
      Us[a][mm] = U_W[(size_t)(r * 64 + a) * 64 + mm];
      Tb[a][mm] = Tbuf[(((size_t)r * NOUT + o) * 64 + a) * 64 + mm];
    }
    __syncthreads();
    for (int mm = 0; mm < 64; ++mm) {
      float av[4], bv[4];
#pragma unroll
      for (int i = 0; i < 4; ++i) av[i] = Us[ty * 4 + i][mm];
#pragma unroll
      for (int j = 0; j < 4; ++j) bv[j] = Tb[mm][tx * 4 + j];
#pragma unroll
      for (int i = 0; i < 4; ++i)
#pragma unroll
        for (int j = 0; j < 4; ++j) acc[i][j] = fmaf(av[i], bv[j], acc[i][j]);
    }
    __syncthreads();
  }
#pragma unroll
  for (int i = 0; i < 4; ++i)
#pragma unroll
    for (int j = 0; j < 4; ++j) Q[ty * 4 + i][tx * 4 + j] = acc[i][j];
  __syncthreads();
  int ot = o >> 4, o15 = o & 15;
  for (int idx = tid; idx < NGRP * 8; idx += 256) {
    int g = idx >> 3, e = idx & 7;
    int2 ml = gtab[g];
    int m = ml.x, l = ml.y + e;
    float v;
    if (l < 64) v = (m == l) ? Q[m][m] : Q[m][l] + Q[l][m];
    else if (l == 64) v = (m == 64) ? (cbuf[o] + b_out[o]) : linbuf[o * 64 + m];
    else v = 0.f;
    int c = g >> 2, g4 = g & 3;
    Bfrag[((((size_t)c * 3 + ot) * 64) + g4 * 16 + o15) * 8 + e] = f2bf(v);
  }
}

// ---------------- logits via MFMA + fused expmap0/proj/log_softmax ----------------
__global__ __launch_bounds__(256) void k_logits(const ushort* __restrict__ hbf,
                                                const ushort* __restrict__ Bfrag,
                                                const int2* __restrict__ gtab,
                                                float* __restrict__ out, int N) {
  __shared__ float eh[128][77];
  __shared__ int2 gs[NGRP];
  int tid = threadIdx.x;
  int n0 = blockIdx.x * 128;
  for (int idx = tid; idx < 128 * 16; idx += 256) {
    int n = idx >> 4, f4 = (idx & 15) << 2;
    int gn = n0 + n;
    float v0 = 0.f, v1 = 0.f, v2 = 0.f, v3 = 0.f;
    if (gn < N) {
      ushort4 u = *(const ushort4*)&hbf[(size_t)gn * HD + f4];
      v0 = bf2f(u.x); v1 = bf2f(u.y); v2 = bf2f(u.z); v3 = bf2f(u.w);
    }
    eh[n][f4] = v0; eh[n][f4 + 1] = v1; eh[n][f4 + 2] = v2; eh[n][f4 + 3] = v3;
  }
  for (int idx = tid; idx < 128 * 13; idx += 256) {
    int n = idx / 13, j = idx - n * 13;
    eh[n][64 + j] = (j == 0) ? 1.f : 0.f;
  }
  for (int idx = tid; idx < NGRP; idx += 256) gs[idx] = gtab[idx];
  __syncthreads();

  int w = tid >> 6, lane = tid & 63;
  int g4 = lane >> 4, c15 = lane & 15;
  float4v acc[2][3];
#pragma unroll
  for (int t = 0; t < 2; ++t)
#pragma unroll
    for (int ot = 0; ot < 3; ++ot) acc[t][ot] = (float4v){0.f, 0.f, 0.f, 0.f};
  const float* ehr0 = &eh[(w * 2 + 0) * 16 + c15][0];
  const float* ehr1 = &eh[(w * 2 + 1) * 16 + c15][0];

  for (int c = 0; c < NCHUNK; ++c) {
    const short8v b0 = *(const short8v*)&Bfrag[(((size_t)c * 3 + 0) * 64 + lane) * 8];
    const short8v b1 = *(const short8v*)&Bfrag[(((size_t)c * 3 + 1) * 64 + lane) * 8];
    const short8v b2 = *(const short8v*)&Bfrag[(((size_t)c * 3 + 2) * 64 + lane) * 8];
    int2 ml = gs[c * 4 + g4];
    int m = ml.x, l0 = ml.y;
    float hm0 = ehr0[m], hm1 = ehr1[m];
    short8v a0, a1;
#pragma unroll
    for (int e = 0; e < 8; ++e) {
      a0[e] = (short)f2bf(hm0 * ehr0[l0 + e]);
      a1[e] = (short)f2bf(hm1 * ehr1[l0 + e]);
    }
    acc[0][0] = __builtin_amdgcn_mfma_f32_16x16x32_bf16(a0, b0, acc[0][0], 0, 0, 0);
    acc[1][0] = __builtin_amdgcn_mfma_f32_16x16x32_bf16(a1, b0, acc[1][0], 0, 0, 0);
    acc[0][1] = __builtin_amdgcn_mfma_f32_16x16x32_bf16(a0, b1, acc[0][1], 0, 0, 0);
    acc[1][1] = __builtin_amdgcn_mfma_f32_16x16x32_bf16(a1, b1, acc[1][1], 0, 0, 0);
    acc[0][2] = __builtin_amdgcn_mfma_f32_16x16x32_bf16(a0, b2, acc[0][2], 0, 0, 0);
    acc[1][2] = __builtin_amdgcn_mfma_f32_16x16x32_bf16(a1, b2, acc[1][2], 0, 0, 0);
  }

  __syncthreads();  // all eh reads done; reuse as logits tile [128][41]
  float* ls = &eh[0][0];
#pragma unroll
  for (int t = 0; t < 2; ++t) {
    int rbase = (w * 2 + t) * 16 + g4 * 4;
#pragma unroll
    for (int ot = 0; ot < 3; ++ot) {
      int o = ot * 16 + c15;
      if (o < NOUT) {
#pragma unroll
        for (int r = 0; r < 4; ++r) ls[(rbase + r) * 41 + o] = acc[t][ot][r];
      }
    }
  }
  __syncthreads();
  if (tid < 128) {
    int n = n0 + tid;
    if (n < N) {
      float v[40];
      float s = 0.f;
#pragma unroll
      for (int i = 0; i < 40; ++i) { v[i] = ls[tid * 41 + i]; s = fmaf(v[i], v[i], s); }
      float un = fmaxf(sqrtf(s), 1e-15f);
      float sc = tanhf(un) / un;
      float s2 = 0.f;
#pragma unroll
      for (int i = 0; i < 40; ++i) { v[i] *= sc; s2 = fmaf(v[i], v[i], s2); }
      float ny = fmaxf(sqrtf(s2), 1e-15f);
      float maxn = 1.0f - 4e-3f;
      if (ny > maxn) {
        float f = maxn / ny;
#pragma unroll
        for (int i = 0; i < 40; ++i) v[i] *= f;
      }
      float vmax = v[0];
#pragma unroll
      for (int i = 1; i < 40; ++i) vmax = fmaxf(vmax, v[i]);
      float se = 0.f;
#pragma unroll
      for (int i = 0; i < 40; ++i) se += expf(v[i] - vmax);
      float lse = logf(se) + vmax;
      float4* q = (float4*)(out + (size_t)n * NOUT);
#pragma unroll
      for (int i = 0; i < 10; ++i) {
        float4 t;
        t.x = v[4 * i] - lse;
        t.y = v[4 * i + 1] - lse;
        t.z = v[4 * i + 2] - lse;
        t.w = v[4 * i + 3] - lse;
        q[i] = t;
      }
    }
  }
}

extern "C" void kernel_launch(void* const* d_in, const int* in_sizes, int n_in,
                              void* d_out, int out_size, void* d_ws, size_t ws_size,
                              hipStream_t stream) {
  const float* x = (const float*)d_in[0];
  const int* erow = (const int*)d_in[1];
  const int* ecol = (const int*)d_in[2];
  const float* ew = (const float*)d_in[3];
  const float* W_in = (const float*)d_in[4];
  const float* b_in = (const float*)d_in[5];
  const float* conv_W = (const float*)d_in[6];
  const float* U_W = (const float*)d_in[7];
  const float* U_b = (const float*)d_in[8];
  const float* V_W = (const float*)d_in[9];
  const float* V_b = (const float*)d_in[10];
  const float* W_out = (const float*)d_in[11];
  const float* b_out = (const float*)d_in[12];
  int N = in_sizes[0] / F_IN;
  int E = in_sizes[1];
  float* out = (float*)d_out;
  int EPAD = E + 8 * N;  // upper bound on padded edge count

  char* base = (char*)d_ws;
  size_t off = 0;
  auto alloc = [&](size_t bytes) -> void* {
    void* p = base + off;
    off += (bytes + 255) & ~(size_t)255;
    return p;
  };
  ushort* h0bf = (ushort*)alloc((size_t)N * HD * 2);
  ushort* hbfA = (ushort*)alloc((size_t)N * HD * 2);
  ushort* hbfB = (ushort*)alloc((size_t)N * HD * 2);
  int* rowptr = (int*)alloc((size_t)(N + 1) * 4);
  int* cursor = (int*)alloc((size_t)N * 4);
  int* counts = (int*)alloc((size_t)N * 4);
  int2* colw = (int2*)alloc((size_t)EPAD * 8);
  float* Tbuf = (float*)alloc((size_t)NRANK * NOUT * 64 * 64 * 4);
  ushort* Bfrag = (ushort*)alloc((size_t)NCHUNK * 3 * 64 * 8 * 2);
  ushort* Wbf = (ushort*)alloc((size_t)64 * 512 * 2);
  ushort* Mfrag = (ushort*)alloc((size_t)NL * 512 * 8 * 2);
  float* linbuf = (float*)alloc(NOUT * 64 * 4);
  float* cbuf = (float*)alloc(NOUT * 4);
  int2* gtab = (int2*)alloc(NGRP * 8);
  int* bsum = (int*)alloc(64 * 4);
  int* boff = (int*)alloc(64 * 4);

  int G = (N + 1023) / 1024;

  k_zero<<<(N + 255) / 256, 256, 0, stream>>>(counts, linbuf, cbuf, (ushort4*)Bfrag, colw, EPAD, N);
  k_count<<<(E + 255) / 256, 256, 0, stream>>>(erow, counts, E);
  k_scan1<<<G, 1024, 0, stream>>>(counts, rowptr, bsum, N);
  k_scan2<<<1, 64, 0, stream>>>(bsum, boff, G);
  k_scan3<<<G, 1024, 0, stream>>>(rowptr, cursor, boff, counts, N);
  k_fill<<<(E + 255) / 256, 256, 0, stream>>>(erow, ecol, ew, cursor, colw, E);
  k_wcvt<<<128, 256, 0, stream>>>(W_in, Wbf);
  k_gemm_in<<<(N + 63) / 64, 256, 0, stream>>>(x, Wbf, b_in, h0bf, N);
  k_mpack<<<NL, 256, 0, stream>>>(conv_W, Mfrag);
  k_gtab<<<1, 512, 0, stream>>>(gtab);
  k_T<<<NRANK * NOUT, 256, 0, stream>>>(W_out, V_W, V_b, U_W, U_b, Tbuf, linbuf, cbuf);
  k_Q<<<NOUT, 256, 0, stream>>>(U_W, Tbuf, linbuf, cbuf, b_out, gtab, Bfrag);

  const ushort* hin = h0bf;
  ushort* hout = hbfA;
  for (int l = 0; l < NL; ++l) {
    k_layer<<<(N + 31) / 32, 256, 0, stream>>>(hin, h0bf, rowptr, colw,
                                               Mfrag + (size_t)l * 512 * 8,
                                               hout, N);
    hin = hout;
    hout = (hout == hbfA) ? hbfB : hbfA;
  }
  k_logits<<<(N + 127) / 128, 256, 0, stream>>>(hin, Bfrag, gtab, out, N);
}

// Round 8
// 477.848 us; speedup vs baseline: 1.1123x; 1.1050x over previous
//
#include <hip/hip_runtime.h>
#include <cmath>

#define F_IN 500
#define HD 64
#define NL 8
#define NRANK 3
#define NOUT 40
#define NGRP 300   // 297 real (m,l0) groups of 8 + 3 zero pads -> K = 2400
#define NCHUNK 75  // 2400 / 32

typedef __attribute__((ext_vector_type(8))) short short8v;
typedef __attribute__((ext_vector_type(4))) float float4v;

__device__ __forceinline__ float bf2f(ushort u) {
  union { unsigned int i; float f; } v;
  v.i = ((unsigned int)u) << 16;
  return v.f;
}
__device__ __forceinline__ float bflo(unsigned int u) {
  union { unsigned int i; float f; } v;
  v.i = u << 16;
  return v.f;
}
__device__ __forceinline__ float bfhi(unsigned int u) {
  union { unsigned int i; float f; } v;
  v.i = u & 0xffff0000u;
  return v.f;
}
__device__ __forceinline__ ushort f2bf(float f) {
  union { float f; unsigned int i; } v;
  v.f = f;
  unsigned int b = v.i;
  return (ushort)((b + 0x7FFFu + ((b >> 16) & 1u)) >> 16);
}

// ---------------- zero init (counts, bias bufs, Bfrag, padded colw) ----------------
__global__ __launch_bounds__(256) void k_zero(int* counts, float* linbuf, float* cbuf,
                                              ushort4* bfrag4, int2* colw, int epad, int N) {
  int i = blockIdx.x * 256 + threadIdx.x;
  if (i < N) counts[i] = 0;
  if (i < NOUT * HD) linbuf[i] = 0.f;
  if (i < NOUT) cbuf[i] = 0.f;
  if (i < NCHUNK * 3 * 64 * 2) bfrag4[i] = make_ushort4(0, 0, 0, 0);
  for (int j = i; j < epad; j += gridDim.x * 256) colw[j] = make_int2(0, 0);
}

__global__ __launch_bounds__(256) void k_count(const int* __restrict__ row, int* counts, int E) {
  int e = blockIdx.x * 256 + threadIdx.x;
  if (e < E) atomicAdd(&counts[row[e]], 1);
}

// ---------------- parallel scan over degrees PADDED to 16 (3 kernels) ----------------
__global__ __launch_bounds__(1024) void k_scan1(const int* __restrict__ counts, int* __restrict__ rowptr,
                                                int* __restrict__ bsum, int N) {
  __shared__ int sh[1024];
  int t = threadIdx.x, i = blockIdx.x * 1024 + t;
  int c = (i < N) ? ((counts[i] + 15) & ~15) : 0;
  sh[t] = c;
  __syncthreads();
  for (int d = 1; d < 1024; d <<= 1) {
    int v = (t >= d) ? sh[t - d] : 0;
    __syncthreads();
    sh[t] += v;
    __syncthreads();
  }
  if (i < N) rowptr[i] = sh[t] - c;  // block-local exclusive
  if (t == 1023) bsum[blockIdx.x] = sh[1023];
}

__global__ __launch_bounds__(64) void k_scan2(const int* __restrict__ bsum, int* __restrict__ boff, int G) {
  int t = threadIdx.x;
  int base = 0;
  for (int s = 0; s < G; s += 64) {
    int i = s + t;
    int v = (i < G) ? bsum[i] : 0;
    int orig = v;
    for (int d = 1; d < 64; d <<= 1) {
      int u = __shfl_up(v, d, 64);
      if (t >= d) v += u;
    }
    if (i < G) boff[i] = base + v - orig;
    base += __shfl(v, 63, 64);
  }
}

__global__ __launch_bounds__(1024) void k_scan3(int* __restrict__ rowptr, int* __restrict__ cursor,
                                                const int* __restrict__ boff,
                                                const int* __restrict__ counts, int N) {
  int i = blockIdx.x * 1024 + threadIdx.x;
  if (i < N) {
    int v = rowptr[i] + boff[blockIdx.x];
    rowptr[i] = v;
    cursor[i] = v;
    if (i == N - 1) rowptr[N] = v + ((counts[i] + 15) & ~15);
  }
}

__global__ __launch_bounds__(256) void k_fill(const int* __restrict__ row, const int* __restrict__ col,
                                              const float* __restrict__ w, int* cursor,
                                              int2* __restrict__ colw, int E) {
  int e = blockIdx.x * 256 + threadIdx.x;
  if (e < E) {
    int r = row[e];
    int p = atomicAdd(&cursor[r], 1);
    colw[p] = make_int2(col[e] * HD, __float_as_int(w[e]));  // pre-scaled element offset
  }
}

// ---------------- W_in -> bf16 [64 cols][512 k], zero-padded ----------------
__global__ __launch_bounds__(256) void k_wcvt(const float* __restrict__ W, ushort* __restrict__ Wbf) {
  int i = blockIdx.x * 256 + threadIdx.x;
  if (i >= 64 * 512) return;
  int d = i >> 9, k = i & 511;
  Wbf[i] = (k < F_IN) ? f2bf(W[(size_t)k * HD + d]) : (ushort)0;
}

// ---------------- input GEMM via MFMA, register-rotated 2-chunk pipeline, 1 wave/block ----------------
__global__ __launch_bounds__(64) void k_gemm_in(const float* __restrict__ x,
                                                const ushort* __restrict__ Wbf,
                                                const float* __restrict__ b,
                                                ushort* __restrict__ h0bf, int N) {
  int lane = threadIdx.x;
  int c15 = lane & 15, g4 = lane >> 4;
  int rowA = blockIdx.x * 16 + c15;
  if (rowA >= N) rowA = N - 1;  // clamp; results discarded at store
  const float* xr = x + (size_t)rowA * F_IN;
  int koff = g4 * 8;
  float4v acc[4];
#pragma unroll
  for (int ct = 0; ct < 4; ++ct) acc[ct] = (float4v){0.f, 0.f, 0.f, 0.f};

  // pipeline over full chunks 0..14; chunk 15 (masked tail) peeled
  float4 fa0 = *(const float4*)(xr + koff);
  float4 fa1 = *(const float4*)(xr + koff + 4);
  float4 fb0 = *(const float4*)(xr + 32 + koff);
  float4 fb1 = *(const float4*)(xr + 32 + koff + 4);
#pragma unroll
  for (int kc = 0; kc < 15; ++kc) {
    float4 c0 = fa0, c1 = fa1;
    fa0 = fb0; fa1 = fb1;
    if (kc + 2 < 15) {
      const float* p = xr + (kc + 2) * 32 + koff;
      fb0 = *(const float4*)p;
      fb1 = *(const float4*)(p + 4);
    }
    short8v a;
    a[0] = (short)f2bf(c0.x); a[1] = (short)f2bf(c0.y);
    a[2] = (short)f2bf(c0.z); a[3] = (short)f2bf(c0.w);
    a[4] = (short)f2bf(c1.x); a[5] = (short)f2bf(c1.y);
    a[6] = (short)f2bf(c1.z); a[7] = (short)f2bf(c1.w);
    int kbase = kc * 32 + koff;
#pragma unroll
    for (int ct = 0; ct < 4; ++ct) {
      const short8v bb = *(const short8v*)&Wbf[((ct * 16 + c15) << 9) + kbase];
      acc[ct] = __builtin_amdgcn_mfma_f32_16x16x32_bf16(a, bb, acc[ct], 0, 0, 0);
    }
  }
  {  // chunk 15: floats 480..499 valid
    int kbase = 480 + koff;
    short8v a;
#pragma unroll
    for (int e = 0; e < 8; ++e) {
      int k = kbase + e;
      a[e] = (short)(k < F_IN ? f2bf(xr[k]) : (ushort)0);
    }
#pragma unroll
    for (int ct = 0; ct < 4; ++ct) {
      const short8v bb = *(const short8v*)&Wbf[((ct * 16 + c15) << 9) + kbase];
      acc[ct] = __builtin_amdgcn_mfma_f32_16x16x32_bf16(a, bb, acc[ct], 0, 0, 0);
    }
  }
  int mbase = blockIdx.x * 16 + g4 * 4;
#pragma unroll
  for (int ct = 0; ct < 4; ++ct) {
    int d = ct * 16 + c15;
    float bias = b[d];
#pragma unroll
    for (int r = 0; r < 4; ++r) {
      int m = mbase + r;
      if (m < N) {
        float v = acc[ct][r] + bias;
        h0bf[(size_t)m * HD + d] = f2bf(fmaxf(v, 0.f));
      }
    }
  }
}

// ---------------- per-layer matvec matrix in MFMA B-frag layout (once per layer) ----------------
__global__ __launch_bounds__(256) void k_mpack(const float* __restrict__ conv_W, ushort* __restrict__ Mfrag) {
  int l = blockIdx.x;
  const float* convW = conv_W + (size_t)l * HD * HD;
  ushort* out = Mfrag + (size_t)l * 512 * 8;
  float beta = logf(0.5f / (float)(l + 1) + 1.0f);
  int tid = threadIdx.x;
  for (int f = tid; f < 512; f += 256) {
    int kc = f >> 8, ct = (f >> 6) & 3, ln = f & 63;
    int kb = kc * 32 + ((ln >> 4) << 3);
    int col = (ct << 4) + (ln & 15);
    short8v vals;
#pragma unroll
    for (int e = 0; e < 8; ++e) {
      int k = kb + e;
      float v = beta * convW[(k << 6) + col] + ((k == col) ? (1.f - beta) : 0.f);
      vals[e] = (short)f2bf(v);
    }
    *(short8v*)&out[(size_t)f * 8] = vals;
  }
}

// ---------------- GCN2 layer: pair-gathers (2 edges/instr, 16-deep) + MFMA matvec ----------------
__global__ __launch_bounds__(256) void k_layer(const ushort* __restrict__ hin,
                                               const ushort* __restrict__ h0bf,
                                               const int* __restrict__ rowptrP, const int2* __restrict__ colw,
                                               const ushort* __restrict__ MfragL,
                                               ushort* __restrict__ hout, int N) {
  __shared__ ushort mfrag[512][8];
  __shared__ ushort sup[32][72];
  __shared__ ushort outt[32][72];
  int tid = threadIdx.x, wv = tid >> 6, t = tid & 63;
  int half = t >> 5, l31 = t & 31;
  {  // coalesced mfrag load (8 KB)
    const short8v* src = (const short8v*)MfragL;
    short8v* dst = (short8v*)&mfrag[0][0];
    dst[tid] = src[tid];
    dst[tid + 256] = src[tid + 256];
  }
  int n0 = blockIdx.x * 32;
  int base_row = n0 + wv * 8;
  int re = 0;
  if (t < 9) {
    int nn = base_row + t;
    if (nn <= N) re = rowptrP[nn];
  }
  const int4* cw4 = (const int4*)colw;
  for (int rr = 0; rr < 8; ++rr) {
    int rw = wv * 8 + rr;
    int n = n0 + rw;
    if (n < N) {
      int j = __shfl(re, rr, 64);
      int je = __shfl(re, rr + 1, 64);
      float alo = 0.f, ahi = 0.f;
      if (j < je) {
        int bidx = (j >> 1) + half;
        int4 qa = cw4[bidx], qb = cw4[bidx + 2], qc = cw4[bidx + 4], qd = cw4[bidx + 6];
        j += 16;
        for (;;) {
          // 8 pair-gathers back-to-back: each loads ushort2 for THIS half's edge
          unsigned g0 = *(const unsigned*)(hin + (unsigned)qa.x + 2 * l31);
          unsigned g1 = *(const unsigned*)(hin + (unsigned)qa.z + 2 * l31);
          unsigned g2 = *(const unsigned*)(hin + (unsigned)qb.x + 2 * l31);
          unsigned g3 = *(const unsigned*)(hin + (unsigned)qb.z + 2 * l31);
          unsigned g4_ = *(const unsigned*)(hin + (unsigned)qc.x + 2 * l31);
          unsigned g5 = *(const unsigned*)(hin + (unsigned)qc.z + 2 * l31);
          unsigned g6 = *(const unsigned*)(hin + (unsigned)qd.x + 2 * l31);
          unsigned g7 = *(const unsigned*)(hin + (unsigned)qd.z + 2 * l31);
          bool more = j < je;
          int4 pa, pb, pc, pd;
          if (more) {
            int nb = (j >> 1) + half;
            pa = cw4[nb]; pb = cw4[nb + 2]; pc = cw4[nb + 4]; pd = cw4[nb + 6];
          }
          float w0 = __int_as_float(qa.y), w1 = __int_as_float(qa.w);
          float w2 = __int_as_float(qb.y), w3 = __int_as_float(qb.w);
          float w4 = __int_as_float(qc.y), w5 = __int_as_float(qc.w);
          float w6 = __int_as_float(qd.y), w7 = __int_as_float(qd.w);
          alo = fmaf(w0, bflo(g0), alo); ahi = fmaf(w0, bfhi(g0), ahi);
          alo = fmaf(w1, bflo(g1), alo); ahi = fmaf(w1, bfhi(g1), ahi);
          alo = fmaf(w2, bflo(g2), alo); ahi = fmaf(w2, bfhi(g2), ahi);
          alo = fmaf(w3, bflo(g3), alo); ahi = fmaf(w3, bfhi(g3), ahi);
          alo = fmaf(w4, bflo(g4_), alo); ahi = fmaf(w4, bfhi(g4_), ahi);
          alo = fmaf(w5, bflo(g5), alo); ahi = fmaf(w5, bfhi(g5), ahi);
          alo = fmaf(w6, bflo(g6), alo); ahi = fmaf(w6, bfhi(g6), ahi);
          alo = fmaf(w7, bflo(g7), alo); ahi = fmaf(w7, bfhi(g7), ahi);
          if (!more) break;
          qa = pa; qb = pb; qc = pc; qd = pd;
          j += 16;
        }
      }
      // merge the two halves: every lane ends with the full row sum for its element pair
      alo += __shfl_xor(alo, 32);
      ahi += __shfl_xor(ahi, 32);
      unsigned h0p = *(const unsigned*)(h0bf + (size_t)n * HD + 2 * l31);
      float slo = 0.9f * alo + 0.1f * bflo(h0p);
      float shi = 0.9f * ahi + 0.1f * bfhi(h0p);
      if (half == 0) {
        unsigned packed = ((unsigned)f2bf(shi) << 16) | (unsigned)f2bf(slo);
        *(unsigned*)&sup[rw][2 * l31] = packed;
      }
    } else if (half == 0) {
      *(unsigned*)&sup[rw][2 * l31] = 0u;
    }
  }
  __syncthreads();
  // matvec: out = relu(sup @ M) via MFMA
  {
    int rt = wv >> 1, cp = (wv & 1) * 2;
    int c15 = t & 15, g4i = t >> 4;
    const short8v a0 = *(const short8v*)&sup[rt * 16 + c15][g4i * 8];
    const short8v a1 = *(const short8v*)&sup[rt * 16 + c15][32 + g4i * 8];
#pragma unroll
    for (int q = 0; q < 2; ++q) {
      int ct = cp + q;
      const short8v b0 = *(const short8v*)&mfrag[ct * 64 + t][0];
      const short8v b1 = *(const short8v*)&mfrag[256 + ct * 64 + t][0];
      float4v acc = (float4v){0.f, 0.f, 0.f, 0.f};
      acc = __builtin_amdgcn_mfma_f32_16x16x32_bf16(a0, b0, acc, 0, 0, 0);
      acc = __builtin_amdgcn_mfma_f32_16x16x32_bf16(a1, b1, acc, 0, 0, 0);
#pragma unroll
      for (int r = 0; r < 4; ++r) {
        int row = rt * 16 + g4i * 4 + r;
        outt[row][ct * 16 + c15] = f2bf(fmaxf(acc[r], 0.f));
      }
    }
  }
  __syncthreads();
  {
    int row = tid >> 3, c0 = (tid & 7) * 8;
    int n = n0 + row;
    if (n < N) *(short8v*)&hout[(size_t)n * HD + c0] = *(const short8v*)&outt[row][c0];
  }
}

// ---------------- group table: g -> (m, l0) ----------------
__global__ __launch_bounds__(512) void k_gtab(int2* __restrict__ gtab) {
  int g = threadIdx.x;
  if (g >= NGRP) return;
  int m = 64, l0 = 65;
  if (g < 297) {
    int cum = 0;
    for (int mm = 0; mm < 65; ++mm) {
      int ng = (65 - mm + 7) >> 3;
      if (g < cum + ng) { m = mm; l0 = mm + (g - cum) * 8; break; }
      cum += ng;
    }
  }
  gtab[g] = make_int2(m, l0);
}

// ---------------- T[r,o] = Wo_o @ V_r^T  (+ linear/const bias terms) ----------------
__global__ __launch_bounds__(256) void k_T(const float* __restrict__ W_out, const float* __restrict__ V_W,
                                           const float* __restrict__ V_b, const float* __restrict__ U_W,
                                           const float* __restrict__ U_b,
                                           float* __restrict__ Tbuf, float* linbuf, float* cbuf) {
  int o = blockIdx.x % NOUT;
  int r = blockIdx.x / NOUT;
  __shared__ float Wo[64][65];
  __shared__ float Vs[64][65];
  __shared__ float t1[64], t2[64];
  int tid = threadIdx.x;
  int tx = tid & 15, ty = tid >> 4;
  for (int idx = tid; idx < 4096; idx += 256) {
    int m = idx >> 6, l = idx & 63;
    Wo[m][l] = W_out[(size_t)idx * NOUT + o];
    Vs[m][l] = V_W[(size_t)(r * 64 + m) * 64 + l];
  }
  __syncthreads();
  float acc[4][4] = {};
  for (int l = 0; l < 64; ++l) {
    float av[4], bv[4];
#pragma unroll
    for (int i = 0; i < 4; ++i) av[i] = Wo[ty * 4 + i][l];
#pragma unroll
    for (int j = 0; j < 4; ++j) bv[j] = Vs[tx * 4 + j][l];
#pragma unroll
    for (int i = 0; i < 4; ++i)
#pragma unroll
      for (int j = 0; j < 4; ++j) acc[i][j] = fmaf(av[i], bv[j], acc[i][j]);
  }
#pragma unroll
  for (int i = 0; i < 4; ++i)
#pragma unroll
    for (int j = 0; j < 4; ++j)
      Tbuf[(((size_t)r * NOUT + o) * 64 + ty * 4 + i) * 64 + tx * 4 + j] = acc[i][j];
  if (tid < 64) {
    float s1 = 0.f, s2 = 0.f;
    for (int l = 0; l < 64; ++l) s1 = fmaf(Wo[tid][l], V_b[r * 64 + l], s1);
    for (int m = 0; m < 64; ++m) s2 = fmaf(Wo[m][tid], U_b[r * 64 + m], s2);
    t1[tid] = s1;
    t2[tid] = s2;
  }
  __syncthreads();
  if (tid < 64) {
    float s = 0.f, s2 = 0.f;
    for (int m = 0; m < 64; ++m) s = fmaf(U_W[(size_t)(r * 64 + tid) * 64 + m], t1[m], s);
    for (int l = 0; l < 64; ++l) s2 = fmaf(Vs[tid][l], t2[l], s2);
    atomicAdd(&linbuf[o * 64 + tid], s + s2);
  }
  if (tid == 0) {
    float s = 0.f;
    for (int m = 0; m < 64; ++m) s = fmaf(U_b[r * 64 + m], t1[m], s);
    atomicAdd(&cbuf[o], s);
  }
}

// ---------------- Q_o = sum_r U_r @ T[r,o]; pack bf16 B-fragments ----------------
__global__ __launch_bounds__(256) void k_Q(const float* __restrict__ U_W, const float* __restrict__ Tbuf,
                                           const float* __restrict__ linbuf, const float* __restrict__ cbuf,
                                           const float* __restrict__ b_out,
                                           const int2* __restrict__ gtab, ushort* __restrict__ Bfrag) {
  int o = blockIdx.x;
  __shared__ float Us[64][65];
  __shared__ float Tb[64][65];
  __shared__ float Q[64][65];
  int tid = threadIdx.x, tx = tid & 15, ty = tid >> 4;
  float acc[4][4] = {};
  for (int r = 0; r < NRANK; ++r) {
    for (int idx = tid; idx < 4096; idx += 256) {
      int a = idx >> 6, mm = idx & 63;
      Us[a][mm] = U_W[(size_t)(r * 64 + a) * 64 + mm];
      Tb[a][mm] = Tbuf[(((size_t)r * NOUT + o) * 64 + a) * 64 + mm];
    }
    __syncthreads();
    for (int mm = 0; mm < 64; ++mm) {
      float av[4], bv[4];
#pragma unroll
      for (int i = 0; i < 4; ++i) av[i] = Us[ty * 4 + i][mm];
#pragma unroll
      for (int j = 0; j < 4; ++j) bv[j] = Tb[mm][tx * 4 + j];
#pragma unroll
      for (int i = 0; i < 4; ++i)
#pragma unroll
        for (int j = 0; j < 4; ++j) acc[i][j] = fmaf(av[i], bv[j], acc[i][j]);
    }
    __syncthreads();
  }
#pragma unroll
  for (int i = 0; i < 4; ++i)
#pragma unroll
    for (int j = 0; j < 4; ++j) Q[ty * 4 + i][tx * 4 + j] = acc[i][j];
  __syncthreads();
  int ot = o >> 4, o15 = o & 15;
  for (int idx = tid; idx < NGRP * 8; idx += 256) {
    int g = idx >> 3, e = idx & 7;
    int2 ml = gtab[g];
    int m = ml.x, l = ml.y + e;
    float v;
    if (l < 64) v = (m == l) ? Q[m][m] : Q[m][l] + Q[l][m];
    else if (l == 64) v = (m == 64) ? (cbuf[o] + b_out[o]) : linbuf[o * 64 + m];
    else v = 0.f;
    int c = g >> 2, g4 = g & 3;
    Bfrag[((((size_t)c * 3 + ot) * 64) + g4 * 16 + o15) * 8 + e] = f2bf(v);
  }
}

// ---------------- logits via MFMA + fused expmap0/proj/log_softmax ----------------
__global__ __launch_bounds__(256) void k_logits(const ushort* __restrict__ hbf,
                                                const ushort* __restrict__ Bfrag,
                                                const int2* __restrict__ gtab,
                                                float* __restrict__ out, int N) {
  __shared__ float eh[128][77];
  __shared__ int2 gs[NGRP];
  int tid = threadIdx.x;
  int n0 = blockIdx.x * 128;
  for (int idx = tid; idx < 128 * 16; idx += 256) {
    int n = idx >> 4, f4 = (idx & 15) << 2;
    int gn = n0 + n;
    float v0 = 0.f, v1 = 0.f, v2 = 0.f, v3 = 0.f;
    if (gn < N) {
      ushort4 u = *(const ushort4*)&hbf[(size_t)gn * HD + f4];
      v0 = bf2f(u.x); v1 = bf2f(u.y); v2 = bf2f(u.z); v3 = bf2f(u.w);
    }
    eh[n][f4] = v0; eh[n][f4 + 1] = v1; eh[n][f4 + 2] = v2; eh[n][f4 + 3] = v3;
  }
  for (int idx = tid; idx < 128 * 13; idx += 256) {
    int n = idx / 13, j = idx - n * 13;
    eh[n][64 + j] = (j == 0) ? 1.f : 0.f;
  }
  for (int idx = tid; idx < NGRP; idx += 256) gs[idx] = gtab[idx];
  __syncthreads();

  int w = tid >> 6, lane = tid & 63;
  int g4 = lane >> 4, c15 = lane & 15;
  float4v acc[2][3];
#pragma unroll
  for (int t = 0; t < 2; ++t)
#pragma unroll
    for (int ot = 0; ot < 3; ++ot) acc[t][ot] = (float4v){0.f, 0.f, 0.f, 0.f};
  const float* ehr0 = &eh[(w * 2 + 0) * 16 + c15][0];
  const float* ehr1 = &eh[(w * 2 + 1) * 16 + c15][0];

  for (int c = 0; c < NCHUNK; ++c) {
    const short8v b0 = *(const short8v*)&Bfrag[(((size_t)c * 3 + 0) * 64 + lane) * 8];
    const short8v b1 = *(const short8v*)&Bfrag[(((size_t)c * 3 + 1) * 64 + lane) * 8];
    const short8v b2 = *(const short8v*)&Bfrag[(((size_t)c * 3 + 2) * 64 + lane) * 8];
    int2 ml = gs[c * 4 + g4];
    int m = ml.x, l0 = ml.y;
    float hm0 = ehr0[m], hm1 = ehr1[m];
    short8v a0, a1;
#pragma unroll
    for (int e = 0; e < 8; ++e) {
      a0[e] = (short)f2bf(hm0 * ehr0[l0 + e]);
      a1[e] = (short)f2bf(hm1 * ehr1[l0 + e]);
    }
    acc[0][0] = __builtin_amdgcn_mfma_f32_16x16x32_bf16(a0, b0, acc[0][0], 0, 0, 0);
    acc[1][0] = __builtin_amdgcn_mfma_f32_16x16x32_bf16(a1, b0, acc[1][0], 0, 0, 0);
    acc[0][1] = __builtin_amdgcn_mfma_f32_16x16x32_bf16(a0, b1, acc[0][1], 0, 0, 0);
    acc[1][1] = __builtin_amdgcn_mfma_f32_16x16x32_bf16(a1, b1, acc[1][1], 0, 0, 0);
    acc[0][2] = __builtin_amdgcn_mfma_f32_16x16x32_bf16(a0, b2, acc[0][2], 0, 0, 0);
    acc[1][2] = __builtin_amdgcn_mfma_f32_16x16x32_bf16(a1, b2, acc[1][2], 0, 0, 0);
  }

  __syncthreads();  // all eh reads done; reuse as logits tile [128][41]
  float* ls = &eh[0][0];
#pragma unroll
  for (int t = 0; t < 2; ++t) {
    int rbase = (w * 2 + t) * 16 + g4 * 4;
#pragma unroll
    for (int ot = 0; ot < 3; ++ot) {
      int o = ot * 16 + c15;
      if (o < NOUT) {
#pragma unroll
        for (int r = 0; r < 4; ++r) ls[(rbase + r) * 41 + o] = acc[t][ot][r];
      }
    }
  }
  __syncthreads();
  if (tid < 128) {
    int n = n0 + tid;
    if (n < N) {
      float v[40];
      float s = 0.f;
#pragma unroll
      for (int i = 0; i < 40; ++i) { v[i] = ls[tid * 41 + i]; s = fmaf(v[i], v[i], s); }
      float un = fmaxf(sqrtf(s), 1e-15f);
      float sc = tanhf(un) / un;
      float s2 = 0.f;
#pragma unroll
      for (int i = 0; i < 40; ++i) { v[i] *= sc; s2 = fmaf(v[i], v[i], s2); }
      float ny = fmaxf(sqrtf(s2), 1e-15f);
      float maxn = 1.0f - 4e-3f;
      if (ny > maxn) {
        float f = maxn / ny;
#pragma unroll
        for (int i = 0; i < 40; ++i) v[i] *= f;
      }
      float vmax = v[0];
#pragma unroll
      for (int i = 1; i < 40; ++i) vmax = fmaxf(vmax, v[i]);
      float se = 0.f;
#pragma unroll
      for (int i = 0; i < 40; ++i) se += expf(v[i] - vmax);
      float lse = logf(se) + vmax;
      float4* q = (float4*)(out + (size_t)n * NOUT);
#pragma unroll
      for (int i = 0; i < 10; ++i) {
        float4 t;
        t.x = v[4 * i] - lse;
        t.y = v[4 * i + 1] - lse;
        t.z = v[4 * i + 2] - lse;
        t.w = v[4 * i + 3] - lse;
        q[i] = t;
      }
    }
  }
}

extern "C" void kernel_launch(void* const* d_in, const int* in_sizes, int n_in,
                              void* d_out, int out_size, void* d_ws, size_t ws_size,
                              hipStream_t stream) {
  const float* x = (const float*)d_in[0];
  const int* erow = (const int*)d_in[1];
  const int* ecol = (const int*)d_in[2];
  const float* ew = (const float*)d_in[3];
  const float* W_in = (const float*)d_in[4];
  const float* b_in = (const float*)d_in[5];
  const float* conv_W = (const float*)d_in[6];
  const float* U_W = (const float*)d_in[7];
  const float* U_b = (const float*)d_in[8];
  const float* V_W = (const float*)d_in[9];
  const float* V_b = (const float*)d_in[10];
  const float* W_out = (const float*)d_in[11];
  const float* b_out = (const float*)d_in[12];
  int N = in_sizes[0] / F_IN;
  int E = in_sizes[1];
  float* out = (float*)d_out;
  int EPAD = E + 16 * N;  // upper bound on padded edge count

  char* base = (char*)d_ws;
  size_t off = 0;
  auto alloc = [&](size_t bytes) -> void* {
    void* p = base + off;
    off += (bytes + 255) & ~(size_t)255;
    return p;
  };
  ushort* h0bf = (ushort*)alloc((size_t)N * HD * 2);
  ushort* hbfA = (ushort*)alloc((size_t)N * HD * 2);
  ushort* hbfB = (ushort*)alloc((size_t)N * HD * 2);
  int* rowptr = (int*)alloc((size_t)(N + 1) * 4);
  int* cursor = (int*)alloc((size_t)N * 4);
  int* counts = (int*)alloc((size_t)N * 4);
  int2* colw = (int2*)alloc((size_t)EPAD * 8);
  float* Tbuf = (float*)alloc((size_t)NRANK * NOUT * 64 * 64 * 4);
  ushort* Bfrag = (ushort*)alloc((size_t)NCHUNK * 3 * 64 * 8 * 2);
  ushort* Wbf = (ushort*)alloc((size_t)64 * 512 * 2);
  ushort* Mfrag = (ushort*)alloc((size_t)NL * 512 * 8 * 2);
  float* linbuf = (float*)alloc(NOUT * 64 * 4);
  float* cbuf = (float*)alloc(NOUT * 4);
  int2* gtab = (int2*)alloc(NGRP * 8);
  int* bsum = (int*)alloc(64 * 4);
  int* boff = (int*)alloc(64 * 4);

  int G = (N + 1023) / 1024;

  k_zero<<<(N + 255) / 256, 256, 0, stream>>>(counts, linbuf, cbuf, (ushort4*)Bfrag, colw, EPAD, N);
  k_count<<<(E + 255) / 256, 256, 0, stream>>>(erow, counts, E);
  k_scan1<<<G, 1024, 0, stream>>>(counts, rowptr, bsum, N);
  k_scan2<<<1, 64, 0, stream>>>(bsum, boff, G);
  k_scan3<<<G, 1024, 0, stream>>>(rowptr, cursor, boff, counts, N);
  k_fill<<<(E + 255) / 256, 256, 0, stream>>>(erow, ecol, ew, cursor, colw, E);
  k_wcvt<<<128, 256, 0, stream>>>(W_in, Wbf);
  k_gemm_in<<<(N + 15) / 16, 64, 0, stream>>>(x, Wbf, b_in, h0bf, N);
  k_mpack<<<NL, 256, 0, stream>>>(conv_W, Mfrag);
  k_gtab<<<1, 512, 0, stream>>>(gtab);
  k_T<<<NRANK * NOUT, 256, 0, stream>>>(W_out, V_W, V_b, U_W, U_b, Tbuf, linbuf, cbuf);
  k_Q<<<NOUT, 256, 0, stream>>>(U_W, Tbuf, linbuf, cbuf, b_out, gtab, Bfrag);

  const ushort* hin = h0bf;
  ushort* hout = hbfA;
  for (int l = 0; l < NL; ++l) {
    k_layer<<<(N + 31) / 32, 256, 0, stream>>>(hin, h0bf, rowptr, colw,
                                               Mfrag + (size_t)l * 512 * 8,
                                               hout, N);
    hin = hout;
    hout = (hout == hbfA) ? hbfB : hbfA;
  }
  k_logits<<<(N + 127) / 128, 256, 0, stream>>>(hin, Bfrag, gtab, out, N);
}